// Round 1
// baseline (642.772 us; speedup 1.0000x reference)
//
#include <hip/hip_runtime.h>

#define N_NODES 100000
#define KN 32
#define EPS 1e-5f

// ---------------- workspace layout (float offsets) ----------------
#define OFF_X0   0          // [N]        normalized scalar input
#define OFF_S4   100000     // [N]*4      layer0 per-head weighted sums (float4)
#define OFF_XE   500000     // [N*20]     xe rows, padded stride 20 (reused layer1/2)
#define OFF_Q4   2500000    // [N]*4      drain projections (float4)
#define OFF_X2   2900000    // [N*18]     layer1 raw output
#define OFF_Y    4700000    // [N*18]     layer2 raw output
#define OFF_T    6500000    // [128]      stats accumulators (memset to 0 each call)
#define OFF_P    6500128    // [1024]     derived params
// stats layout in T: 0:sum_x 1:ss_x | 2..4 sum_S 5..7 ss_S | 8..25 sum_x2 26..43 ss_x2 | 44..61 sum_y 62..79 ss_y
// params in P: 0 s0, 1 t0 | 2..4 A | 5..7 B | 8..10 C | 11 ew0, 12 ew1
//              16..87 M1(4x18), 88..105 c1 | 112..507 M2(22x18), 508..525 c2 | 528..545 wf, 546 cf

// ---------------- generic channel stats: sum & sumsq ----------------
template<int C, int STRIDE>
__global__ void stats_kernel(const float* __restrict__ in, float* __restrict__ acc, int n) {
    float s[C], ss[C];
#pragma unroll
    for (int c = 0; c < C; ++c) { s[c] = 0.f; ss[c] = 0.f; }
    for (int i = blockIdx.x * blockDim.x + threadIdx.x; i < n; i += gridDim.x * blockDim.x) {
#pragma unroll
        for (int c = 0; c < C; ++c) {
            float v = in[(size_t)i * STRIDE + c];
            s[c] += v; ss[c] = fmaf(v, v, ss[c]);
        }
    }
#pragma unroll
    for (int c = 0; c < C; ++c) {
        for (int off = 32; off > 0; off >>= 1) {
            s[c]  += __shfl_xor(s[c],  off, 64);
            ss[c] += __shfl_xor(ss[c], off, 64);
        }
    }
    if ((threadIdx.x & 63) == 0) {
#pragma unroll
        for (int c = 0; c < C; ++c) {
            atomicAdd(&acc[c], s[c]);
            atomicAdd(&acc[C + c], ss[c]);
        }
    }
}

// ---------------- prep0: BN0 fold + layer0 score constants ----------------
__global__ void prep0_kernel(const float* __restrict__ T, float* __restrict__ P,
                             const float* g0, const float* be0,
                             const float* W0, const float* b0,
                             const float* aW0, const float* ab0) {
    if (threadIdx.x || blockIdx.x) return;
    float mu  = T[0] / (float)N_NODES;
    float var = T[1] / (float)N_NODES - mu * mu;
    float inv = rsqrtf(var + EPS);
    float s0 = inv * g0[0];
    P[0] = s0; P[1] = be0[0] - mu * s0;
    for (int h = 0; h < 3; ++h) {
        float A = 0.f, B = 0.f, Cc = 0.f;
        for (int f = 0; f < 6; ++f) {
            A  = fmaf(W0[h * 6 + f], aW0[f], A);
            B  = fmaf(W0[h * 6 + f], aW0[6 + f], B);
            Cc = fmaf(b0[h * 6 + f], aW0[f] + aW0[6 + f], Cc);
        }
        P[2 + h] = A; P[5 + h] = B; P[8 + h] = Cc + ab0[0];
    }
    P[11] = aW0[12]; P[12] = aW0[13];
}

// ---------------- x0 = BN0(x) ----------------
__global__ void x0_kernel(const float* __restrict__ x, const float* __restrict__ P,
                          float* __restrict__ x0) {
    int i = blockIdx.x * blockDim.x + threadIdx.x;
    if (i < N_NODES) x0[i] = fmaf(x[i], P[0], P[1]);
}

// ---------------- layer0 attention: edge-per-lane, 2 nodes/wave ----------------
__global__ __launch_bounds__(256)
void att0_kernel(const float* __restrict__ x0,
                 const int* __restrict__ ei0, const int* __restrict__ ei1,
                 const float2* __restrict__ e2,
                 const float* __restrict__ P, float4* __restrict__ S4) {
    int node = blockIdx.x * 8 + (threadIdx.x >> 5);
    int k = threadIdx.x & 31;
    if (node >= N_NODES) return;
    int eidx = node * KN + k;
    int s = ei0[eidx], d = ei1[eidx];
    float xs = x0[s], xd = x0[d];
    float2 ef = e2[eidx];
    float eb = fmaf(ef.x, P[11], ef.y * P[12]);
    float sc0 = fmaf(xs, P[2], fmaf(xd, P[5], P[8]  + eb));
    float sc1 = fmaf(xs, P[3], fmaf(xd, P[6], P[9]  + eb));
    float sc2 = fmaf(xs, P[4], fmaf(xd, P[7], P[10] + eb));
    float m0 = sc0, m1 = sc1, m2 = sc2;
#pragma unroll
    for (int off = 16; off > 0; off >>= 1) {
        m0 = fmaxf(m0, __shfl_xor(m0, off, 32));
        m1 = fmaxf(m1, __shfl_xor(m1, off, 32));
        m2 = fmaxf(m2, __shfl_xor(m2, off, 32));
    }
    float w0 = __expf(sc0 - m0), w1 = __expf(sc1 - m1), w2 = __expf(sc2 - m2);
    float l0 = w0, l1 = w1, l2 = w2;
    float a0 = w0 * xs, a1 = w1 * xs, a2 = w2 * xs;
#pragma unroll
    for (int off = 16; off > 0; off >>= 1) {
        l0 += __shfl_xor(l0, off, 32); a0 += __shfl_xor(a0, off, 32);
        l1 += __shfl_xor(l1, off, 32); a1 += __shfl_xor(a1, off, 32);
        l2 += __shfl_xor(l2, off, 32); a2 += __shfl_xor(a2, off, 32);
    }
    if (k == 0) S4[node] = make_float4(a0 / l0, a1 / l1, a2 / l2, 0.f);
}

// ---------------- prep1: fold BN1 into M1 (4x18) + c1 ----------------
__global__ void prep1_kernel(const float* __restrict__ T, float* __restrict__ P,
                             const float* W0, const float* b0,
                             const float* g1, const float* be1,
                             const float* W1, const float* b1) {
    __shared__ float alpha[18], beta[18];
    int t = threadIdx.x;
    if (t < 18) {
        int h = t / 6;
        float muS  = T[2 + h] / (float)N_NODES;
        float varS = T[5 + h] / (float)N_NODES - muS * muS;
        float w = W0[t] / (float)KN;
        float inv1 = rsqrtf(varS * w * w + EPS);
        float gg = inv1 * g1[t];
        alpha[t] = w * gg;
        beta[t]  = be1[t] - w * gg * muS;
    }
    __syncthreads();
    if (t < 18) {
        int j = t;
        float* M1 = P + 16; float* c1 = P + 88;
        M1[j] = W1[j];
        for (int h = 0; h < 3; ++h) {
            float acc = 0.f;
            for (int f = 0; f < 6; ++f) acc = fmaf(alpha[h * 6 + f], W1[(1 + h * 6 + f) * 18 + j], acc);
            M1[(1 + h) * 18 + j] = acc;
        }
        float cc = b1[j];
        for (int c = 0; c < 18; ++c) cc = fmaf(beta[c], W1[(1 + c) * 18 + j], cc);
        c1[j] = cc;
    }
}

// ---------------- xe1 = [x0,S] @ M1 + c1 ; q1 ----------------
__global__ void xe1_kernel(const float* __restrict__ x0, const float4* __restrict__ S4,
                           const float* __restrict__ P, const float* __restrict__ aW1,
                           float* __restrict__ xe, float4* __restrict__ q4) {
    int n = blockIdx.x * blockDim.x + threadIdx.x;
    if (n >= N_NODES) return;
    float xv = x0[n];
    float4 S = S4[n];
    const float* M1 = P + 16; const float* c1 = P + 88;
    float row[18];
#pragma unroll
    for (int j = 0; j < 18; ++j) {
        float r = c1[j];
        r = fmaf(xv,  M1[j],      r);
        r = fmaf(S.x, M1[18 + j], r);
        r = fmaf(S.y, M1[36 + j], r);
        r = fmaf(S.z, M1[54 + j], r);
        row[j] = r;
        xe[(size_t)n * 20 + j] = r;
    }
    float q0 = 0.f, q1 = 0.f, q2 = 0.f;
#pragma unroll
    for (int f = 0; f < 6; ++f) {
        float a = aW1[6 + f];
        q0 = fmaf(row[f], a, q0);
        q1 = fmaf(row[6 + f], a, q1);
        q2 = fmaf(row[12 + f], a, q2);
    }
    q4[n] = make_float4(q0, q1, q2, 0.f);
}

// ---------------- generic big attention (layers 1 & 2) ----------------
__global__ __launch_bounds__(256)
void att_big_kernel(const float* __restrict__ xe, const float4* __restrict__ q4,
                    const int* __restrict__ ei0, const int* __restrict__ ei1,
                    const float* __restrict__ aW, const float* __restrict__ abp,
                    float* __restrict__ out) {
    int node = blockIdx.x * 8 + (threadIdx.x >> 5);
    int k = threadIdx.x & 31;
    if (node >= N_NODES) return;
    int eidx = node * KN + k;
    int s = ei0[eidx], d = ei1[eidx];
    const float4* rp = (const float4*)(xe + (size_t)s * 20);
    float4 r0 = rp[0], r1 = rp[1], r2 = rp[2], r3 = rp[3];
    float2 r4 = *(const float2*)(xe + (size_t)s * 20 + 16);
    float4 qd = q4[d];
    float a0 = aW[0], a1 = aW[1], a2 = aW[2], a3 = aW[3], a4 = aW[4], a5 = aW[5];
    float ab = abp[0];
    float sc0 = fmaf(r0.x,a0, fmaf(r0.y,a1, fmaf(r0.z,a2, fmaf(r0.w,a3, fmaf(r1.x,a4, r1.y*a5))))) + qd.x + ab;
    float sc1 = fmaf(r1.z,a0, fmaf(r1.w,a1, fmaf(r2.x,a2, fmaf(r2.y,a3, fmaf(r2.z,a4, r2.w*a5))))) + qd.y + ab;
    float sc2 = fmaf(r3.x,a0, fmaf(r3.y,a1, fmaf(r3.z,a2, fmaf(r3.w,a3, fmaf(r4.x,a4, r4.y*a5))))) + qd.z + ab;
    float m0 = sc0, m1 = sc1, m2 = sc2;
#pragma unroll
    for (int off = 16; off > 0; off >>= 1) {
        m0 = fmaxf(m0, __shfl_xor(m0, off, 32));
        m1 = fmaxf(m1, __shfl_xor(m1, off, 32));
        m2 = fmaxf(m2, __shfl_xor(m2, off, 32));
    }
    float w0 = __expf(sc0 - m0), w1 = __expf(sc1 - m1), w2 = __expf(sc2 - m2);
    float l0 = w0, l1 = w1, l2 = w2;
    float v[18];
    v[0]=w0*r0.x; v[1]=w0*r0.y; v[2]=w0*r0.z; v[3]=w0*r0.w; v[4]=w0*r1.x; v[5]=w0*r1.y;
    v[6]=w1*r1.z; v[7]=w1*r1.w; v[8]=w1*r2.x; v[9]=w1*r2.y; v[10]=w1*r2.z; v[11]=w1*r2.w;
    v[12]=w2*r3.x; v[13]=w2*r3.y; v[14]=w2*r3.z; v[15]=w2*r3.w; v[16]=w2*r4.x; v[17]=w2*r4.y;
#pragma unroll
    for (int off = 16; off > 0; off >>= 1) {
        l0 += __shfl_xor(l0, off, 32);
        l1 += __shfl_xor(l1, off, 32);
        l2 += __shfl_xor(l2, off, 32);
#pragma unroll
        for (int j = 0; j < 18; ++j) v[j] += __shfl_xor(v[j], off, 32);
    }
    if (k == 0) {
        float i0 = 1.f / (l0 * (float)KN);
        float i1 = 1.f / (l1 * (float)KN);
        float i2 = 1.f / (l2 * (float)KN);
        size_t base = (size_t)node * 18;
#pragma unroll
        for (int j = 0; j < 6; ++j) {
            out[base + j]      = v[j] * i0;
            out[base + 6 + j]  = v[6 + j] * i1;
            out[base + 12 + j] = v[12 + j] * i2;
        }
    }
}

// ---------------- prep2: fold BN1+BN2 into M2 (22x18) + c2 ----------------
__global__ void prep2_kernel(const float* __restrict__ T, float* __restrict__ P,
                             const float* W0, const float* b0,
                             const float* g1, const float* be1,
                             const float* g2, const float* be2,
                             const float* W2, const float* b2) {
    __shared__ float alpha[18], beta[18], gam[18], del[18];
    int t = threadIdx.x;
    if (t < 18) {
        int h = t / 6;
        float muS  = T[2 + h] / (float)N_NODES;
        float varS = T[5 + h] / (float)N_NODES - muS * muS;
        float w = W0[t] / (float)KN;
        float inv1 = rsqrtf(varS * w * w + EPS);
        float gg = inv1 * g1[t];
        alpha[t] = w * gg;
        beta[t]  = be1[t] - w * gg * muS;
        float mu2  = T[8 + t]  / (float)N_NODES;
        float var2 = T[26 + t] / (float)N_NODES - mu2 * mu2;
        float inv2 = rsqrtf(var2 + EPS);
        float g = inv2 * g2[t];
        gam[t] = g; del[t] = be2[t] - mu2 * g;
    }
    __syncthreads();
    if (t < 18) {
        int j = t;
        float* M2 = P + 112; float* c2 = P + 508;
        M2[j] = W2[j];
        for (int h = 0; h < 3; ++h) {
            float acc = 0.f;
            for (int f = 0; f < 6; ++f) acc = fmaf(alpha[h * 6 + f], W2[(1 + h * 6 + f) * 18 + j], acc);
            M2[(1 + h) * 18 + j] = acc;
        }
        for (int c = 0; c < 18; ++c) M2[(4 + c) * 18 + j] = gam[c] * W2[(19 + c) * 18 + j];
        float cc = b2[j];
        for (int c = 0; c < 18; ++c) cc = fmaf(beta[c], W2[(1 + c) * 18 + j], cc);
        for (int c = 0; c < 18; ++c) cc = fmaf(del[c],  W2[(19 + c) * 18 + j], cc);
        c2[j] = cc;
    }
}

// ---------------- xe2 = [x0,S,x2raw] @ M2 + c2 ; q2 ----------------
__global__ void xe2_kernel(const float* __restrict__ x0, const float4* __restrict__ S4,
                           const float* __restrict__ x2, const float* __restrict__ P,
                           const float* __restrict__ aW2,
                           float* __restrict__ xe, float4* __restrict__ q4) {
    int n = blockIdx.x * blockDim.x + threadIdx.x;
    if (n >= N_NODES) return;
    float xv = x0[n];
    float4 S = S4[n];
    float xr[18];
#pragma unroll
    for (int c = 0; c < 18; ++c) xr[c] = x2[(size_t)n * 18 + c];
    const float* M2 = P + 112; const float* c2 = P + 508;
    float row[18];
#pragma unroll
    for (int j = 0; j < 18; ++j) {
        float r = c2[j];
        r = fmaf(xv,  M2[j],      r);
        r = fmaf(S.x, M2[18 + j], r);
        r = fmaf(S.y, M2[36 + j], r);
        r = fmaf(S.z, M2[54 + j], r);
#pragma unroll
        for (int c = 0; c < 18; ++c) r = fmaf(xr[c], M2[(4 + c) * 18 + j], r);
        row[j] = r;
        xe[(size_t)n * 20 + j] = r;
    }
    float q0 = 0.f, q1 = 0.f, q2 = 0.f;
#pragma unroll
    for (int f = 0; f < 6; ++f) {
        float a = aW2[6 + f];
        q0 = fmaf(row[f], a, q0);
        q1 = fmaf(row[6 + f], a, q1);
        q2 = fmaf(row[12 + f], a, q2);
    }
    q4[n] = make_float4(q0, q1, q2, 0.f);
}

// ---------------- prepF: fold BN3 into final dot ----------------
__global__ void prepF_kernel(const float* __restrict__ T, float* __restrict__ P,
                             const float* g3, const float* be3,
                             const float* fW, const float* fb) {
    if (threadIdx.x || blockIdx.x) return;
    float cf = fb[0];
    for (int j = 0; j < 18; ++j) {
        float mu  = T[44 + j] / (float)N_NODES;
        float var = T[62 + j] / (float)N_NODES - mu * mu;
        float inv = rsqrtf(var + EPS);
        float g = inv * g3[j];
        P[528 + j] = g * fW[j];
        cf = fmaf(be3[j] - mu * g, fW[j], cf);
    }
    P[546] = cf;
}

// ---------------- final: out = y @ wf + cf ----------------
__global__ void final_kernel(const float* __restrict__ y, const float* __restrict__ P,
                             float* __restrict__ out) {
    int n = blockIdx.x * blockDim.x + threadIdx.x;
    if (n >= N_NODES) return;
    float acc = P[546];
#pragma unroll
    for (int j = 0; j < 18; ++j) acc = fmaf(y[(size_t)n * 18 + j], P[528 + j], acc);
    out[n] = acc;
}

extern "C" void kernel_launch(void* const* d_in, const int* in_sizes, int n_in,
                              void* d_out, int out_size, void* d_ws, size_t ws_size,
                              hipStream_t stream) {
    const float* x   = (const float*)d_in[0];
    const int*   ei  = (const int*)d_in[1];
    const float* e   = (const float*)d_in[2];
    const float* W0  = (const float*)d_in[3];
    const float* b0  = (const float*)d_in[4];
    const float* aW0 = (const float*)d_in[5];
    const float* ab0 = (const float*)d_in[6];
    const float* W1  = (const float*)d_in[7];
    const float* b1  = (const float*)d_in[8];
    const float* aW1 = (const float*)d_in[9];
    const float* ab1 = (const float*)d_in[10];
    const float* W2  = (const float*)d_in[11];
    const float* b2  = (const float*)d_in[12];
    const float* aW2 = (const float*)d_in[13];
    const float* ab2 = (const float*)d_in[14];
    const float* g0  = (const float*)d_in[15];
    const float* be0 = (const float*)d_in[16];
    const float* g1  = (const float*)d_in[17];
    const float* be1 = (const float*)d_in[18];
    const float* g2  = (const float*)d_in[19];
    const float* be2 = (const float*)d_in[20];
    const float* g3  = (const float*)d_in[21];
    const float* be3 = (const float*)d_in[22];
    const float* fW  = (const float*)d_in[23];
    const float* fb  = (const float*)d_in[24];

    const int* ei0 = ei;
    const int* ei1 = ei + (size_t)N_NODES * KN;

    float*  ws = (float*)d_ws;
    float*  x0 = ws + OFF_X0;
    float4* S4 = (float4*)(ws + OFF_S4);
    float*  xe = ws + OFF_XE;
    float4* q4 = (float4*)(ws + OFF_Q4);
    float*  x2 = ws + OFF_X2;
    float*  y  = ws + OFF_Y;
    float*  T  = ws + OFF_T;
    float*  P  = ws + OFF_P;
    float*  out = (float*)d_out;

    hipMemsetAsync(T, 0, 128 * sizeof(float), stream);

    // stage 0: BN0
    stats_kernel<1, 1><<<128, 256, 0, stream>>>(x, T + 0, N_NODES);
    prep0_kernel<<<1, 1, 0, stream>>>(T, P, g0, be0, W0, b0, aW0, ab0);
    x0_kernel<<<(N_NODES + 255) / 256, 256, 0, stream>>>(x, P, x0);

    // layer 0 (rank-1): S per node
    att0_kernel<<<N_NODES / 8, 256, 0, stream>>>(x0, ei0, ei1, (const float2*)e, P, S4);
    stats_kernel<3, 4><<<128, 256, 0, stream>>>((const float*)S4, T + 2, N_NODES);

    // layer 1
    prep1_kernel<<<1, 64, 0, stream>>>(T, P, W0, b0, g1, be1, W1, b1);
    xe1_kernel<<<(N_NODES + 255) / 256, 256, 0, stream>>>(x0, S4, P, aW1, xe, q4);
    att_big_kernel<<<N_NODES / 8, 256, 0, stream>>>(xe, q4, ei0, ei1, aW1, ab1, x2);
    stats_kernel<18, 18><<<128, 256, 0, stream>>>(x2, T + 8, N_NODES);

    // layer 2
    prep2_kernel<<<1, 64, 0, stream>>>(T, P, W0, b0, g1, be1, g2, be2, W2, b2);
    xe2_kernel<<<(N_NODES + 255) / 256, 256, 0, stream>>>(x0, S4, x2, P, aW2, xe, q4);
    att_big_kernel<<<N_NODES / 8, 256, 0, stream>>>(xe, q4, ei0, ei1, aW2, ab2, y);
    stats_kernel<18, 18><<<128, 256, 0, stream>>>(y, T + 44, N_NODES);

    // final BN3 + fc
    prepF_kernel<<<1, 1, 0, stream>>>(T, P, g3, be3, fW, fb);
    final_kernel<<<(N_NODES + 255) / 256, 256, 0, stream>>>(y, P, out);
}

// Round 9
// 368.001 us; speedup vs baseline: 1.7467x; 1.7467x over previous
//
#include <hip/hip_runtime.h>

#define N_NODES 100000
#define KN 32
#define EPS 1e-5f
#define NSLOT 128

// ---------------- workspace layout (float offsets) ----------------
#define OFF_X0   0          // [100000]   normalized scalar input
#define OFF_S4   100000     // [100000*4] layer0 per-head weighted sums (float4)
#define OFF_XE   500000     // [100000*20] xe rows, stride 20 (reused layer1/2)
#define OFF_Q4   2500000    // [100000*4] drain projections (float4)
#define OFF_X2   2900000    // [100000*18] layer1 raw output
#define OFF_Y    4700000    // [100000*18] layer2 raw output
#define OFF_TX   6500000    // [16]   x sum/ss
#define OFF_SS   6500016    // [128*8]  S slotted stats
#define OFF_X2S  6501040    // [128*36] x2 slotted stats
#define OFF_YS   6505648    // [128*36] y slotted stats
#define OFF_P    6510256    // [1024] derived params
// params in P: 0 s0, 1 t0 | 2..4 A | 5..7 B | 8..10 C | 11 ew0, 12 ew1
//              16..87 M1(4x18), 88..105 c1 | 112..507 M2(22x18), 508..525 c2 | 528..545 wf, 546 cf

// ---------------- stats of scalar input x (vectorized) ----------------
__global__ __launch_bounds__(256)
void statsx_kernel(const float4* __restrict__ x4, float* __restrict__ acc) {
    int i = blockIdx.x * 256 + threadIdx.x;
    float s = 0.f, ss = 0.f;
    if (i < 25000) {
        float4 v = x4[i];
        s = v.x + v.y + v.z + v.w;
        ss = v.x * v.x + v.y * v.y + v.z * v.z + v.w * v.w;
    }
#pragma unroll
    for (int off = 32; off > 0; off >>= 1) {
        s  += __shfl_xor(s,  off, 64);
        ss += __shfl_xor(ss, off, 64);
    }
    __shared__ float ls[4], lss[4];
    int wid = threadIdx.x >> 6;
    if ((threadIdx.x & 63) == 0) { ls[wid] = s; lss[wid] = ss; }
    __syncthreads();
    if (threadIdx.x == 0) {
        atomicAdd(&acc[0], ls[0] + ls[1] + ls[2] + ls[3]);
        atomicAdd(&acc[1], lss[0] + lss[1] + lss[2] + lss[3]);
    }
}

// ---------------- prep0: BN0 fold + layer0 score constants ----------------
__global__ void prep0_kernel(const float* __restrict__ T, float* __restrict__ P,
                             const float* g0, const float* be0,
                             const float* W0, const float* b0,
                             const float* aW0, const float* ab0) {
    if (threadIdx.x || blockIdx.x) return;
    float mu  = T[0] / (float)N_NODES;
    float var = T[1] / (float)N_NODES - mu * mu;
    float inv = rsqrtf(var + EPS);
    float s0 = inv * g0[0];
    P[0] = s0; P[1] = be0[0] - mu * s0;
    for (int h = 0; h < 3; ++h) {
        float A = 0.f, B = 0.f, Cc = 0.f;
        for (int f = 0; f < 6; ++f) {
            A  = fmaf(W0[h * 6 + f], aW0[f], A);
            B  = fmaf(W0[h * 6 + f], aW0[6 + f], B);
            Cc = fmaf(b0[h * 6 + f], aW0[f] + aW0[6 + f], Cc);
        }
        P[2 + h] = A; P[5 + h] = B; P[8 + h] = Cc + ab0[0];
    }
    P[11] = aW0[12]; P[12] = aW0[13];
}

// ---------------- x0 = BN0(x), vectorized ----------------
__global__ void x0_kernel(const float4* __restrict__ x4, const float* __restrict__ P,
                          float4* __restrict__ x0) {
    int i = blockIdx.x * blockDim.x + threadIdx.x;
    if (i < 25000) {
        float4 v = x4[i];
        float s = P[0], t = P[1];
        x0[i] = make_float4(fmaf(v.x, s, t), fmaf(v.y, s, t), fmaf(v.z, s, t), fmaf(v.w, s, t));
    }
}

// ---------------- layer0 attention + fused S stats ----------------
__global__ __launch_bounds__(256)
void att0_kernel(const float* __restrict__ x0,
                 const int* __restrict__ ei0, const int* __restrict__ ei1,
                 const float2* __restrict__ e2,
                 const float* __restrict__ P, float4* __restrict__ S4,
                 float* __restrict__ SS) {
    int hw = threadIdx.x >> 5;
    int node = blockIdx.x * 8 + hw;          // grid is exactly N/8 blocks
    int k = threadIdx.x & 31;
    int eidx = node * KN + k;
    int s = ei0[eidx], d = ei1[eidx];
    float xs = x0[s], xd = x0[d];
    float2 ef = e2[eidx];
    float eb = fmaf(ef.x, P[11], ef.y * P[12]);
    float sc0 = fmaf(xs, P[2], fmaf(xd, P[5], P[8]  + eb));
    float sc1 = fmaf(xs, P[3], fmaf(xd, P[6], P[9]  + eb));
    float sc2 = fmaf(xs, P[4], fmaf(xd, P[7], P[10] + eb));
    float m0 = sc0, m1 = sc1, m2 = sc2;
#pragma unroll
    for (int off = 16; off > 0; off >>= 1) {
        m0 = fmaxf(m0, __shfl_xor(m0, off, 32));
        m1 = fmaxf(m1, __shfl_xor(m1, off, 32));
        m2 = fmaxf(m2, __shfl_xor(m2, off, 32));
    }
    float w0 = __expf(sc0 - m0), w1 = __expf(sc1 - m1), w2 = __expf(sc2 - m2);
    float l0 = w0, l1 = w1, l2 = w2;
    float a0 = w0 * xs, a1 = w1 * xs, a2 = w2 * xs;
#pragma unroll
    for (int off = 16; off > 0; off >>= 1) {
        l0 += __shfl_xor(l0, off, 32); a0 += __shfl_xor(a0, off, 32);
        l1 += __shfl_xor(l1, off, 32); a1 += __shfl_xor(a1, off, 32);
        l2 += __shfl_xor(l2, off, 32); a2 += __shfl_xor(a2, off, 32);
    }
    __shared__ float sS[8][4];
    if (k == 0) {
        float v0 = a0 / l0, v1 = a1 / l1, v2 = a2 / l2;
        S4[node] = make_float4(v0, v1, v2, 0.f);
        sS[hw][0] = v0; sS[hw][1] = v1; sS[hw][2] = v2;
    }
    __syncthreads();
    if (threadIdx.x < 3) {
        float ps = 0.f, pss = 0.f;
#pragma unroll
        for (int h = 0; h < 8; ++h) { float v = sS[h][threadIdx.x]; ps += v; pss = fmaf(v, v, pss); }
        int slot = (blockIdx.x & (NSLOT - 1)) * 8;
        atomicAdd(&SS[slot + threadIdx.x], ps);
        atomicAdd(&SS[slot + 4 + threadIdx.x], pss);
    }
}

// ---------------- prep1: reduce S slots, fold BN1 into M1 (4x18) + c1 ----------------
__global__ void prep1_kernel(const float* __restrict__ SS, float* __restrict__ P,
                             const float* W0, const float* g1, const float* be1,
                             const float* W1, const float* b1) {
    __shared__ float muS[3], varS[3], alpha[18], beta[18];
    int t = threadIdx.x;
    if (t < 3) {
        float s = 0.f, ss = 0.f;
#pragma unroll 8
        for (int i = 0; i < NSLOT; ++i) { s += SS[i * 8 + t]; ss += SS[i * 8 + 4 + t]; }
        float mu = s / (float)N_NODES;
        muS[t] = mu; varS[t] = ss / (float)N_NODES - mu * mu;
    }
    __syncthreads();
    if (t < 18) {
        int h = t / 6;
        float w = W0[t] / (float)KN;
        float inv1 = rsqrtf(varS[h] * w * w + EPS);
        float gg = inv1 * g1[t];
        alpha[t] = w * gg;
        beta[t]  = be1[t] - w * gg * muS[h];
    }
    __syncthreads();
    if (t < 18) {
        int j = t;
        float* M1 = P + 16; float* c1 = P + 88;
        M1[j] = W1[j];
        for (int h = 0; h < 3; ++h) {
            float acc = 0.f;
            for (int f = 0; f < 6; ++f) acc = fmaf(alpha[h * 6 + f], W1[(1 + h * 6 + f) * 18 + j], acc);
            M1[(1 + h) * 18 + j] = acc;
        }
        float cc = b1[j];
        for (int c = 0; c < 18; ++c) cc = fmaf(beta[c], W1[(1 + c) * 18 + j], cc);
        c1[j] = cc;
    }
}

// ---------------- xe1 = [x0,S] @ M1 + c1 ; q1 ----------------
__global__ void xe1_kernel(const float* __restrict__ x0, const float4* __restrict__ S4,
                           const float* __restrict__ P, const float* __restrict__ aW1,
                           float* __restrict__ xe, float4* __restrict__ q4) {
    int n = blockIdx.x * blockDim.x + threadIdx.x;
    if (n >= N_NODES) return;
    float xv = x0[n];
    float4 S = S4[n];
    const float* M1 = P + 16; const float* c1 = P + 88;
    float row[18];
#pragma unroll
    for (int j = 0; j < 18; ++j) {
        float r = c1[j];
        r = fmaf(xv,  M1[j],      r);
        r = fmaf(S.x, M1[18 + j], r);
        r = fmaf(S.y, M1[36 + j], r);
        r = fmaf(S.z, M1[54 + j], r);
        row[j] = r;
    }
    float4* xp = (float4*)(xe + (size_t)n * 20);
    xp[0] = make_float4(row[0], row[1], row[2], row[3]);
    xp[1] = make_float4(row[4], row[5], row[6], row[7]);
    xp[2] = make_float4(row[8], row[9], row[10], row[11]);
    xp[3] = make_float4(row[12], row[13], row[14], row[15]);
    *(float2*)(xe + (size_t)n * 20 + 16) = make_float2(row[16], row[17]);
    float q0 = 0.f, q1 = 0.f, q2 = 0.f;
#pragma unroll
    for (int f = 0; f < 6; ++f) {
        float a = aW1[6 + f];
        q0 = fmaf(row[f], a, q0);
        q1 = fmaf(row[6 + f], a, q1);
        q2 = fmaf(row[12 + f], a, q2);
    }
    q4[n] = make_float4(q0, q1, q2, 0.f);
}

// ---------------- big attention (layers 1 & 2) + fused channel stats ----------------
__global__ __launch_bounds__(256)
void att_big_kernel(const float* __restrict__ xe, const float4* __restrict__ q4,
                    const int* __restrict__ ei0, const int* __restrict__ ei1,
                    const float* __restrict__ aW, const float* __restrict__ abp,
                    float* __restrict__ out, float* __restrict__ slots) {
    int hw = threadIdx.x >> 5;
    int node = blockIdx.x * 8 + hw;          // grid exactly N/8
    int k = threadIdx.x & 31;
    int eidx = node * KN + k;
    int s = ei0[eidx], d = ei1[eidx];
    const float4* rp = (const float4*)(xe + (size_t)s * 20);
    float4 r0 = rp[0], r1 = rp[1], r2 = rp[2], r3 = rp[3];
    float2 r4 = *(const float2*)(xe + (size_t)s * 20 + 16);
    float4 qd = q4[d];
    float a0 = aW[0], a1 = aW[1], a2 = aW[2], a3 = aW[3], a4 = aW[4], a5 = aW[5];
    float ab = abp[0];
    float sc0 = fmaf(r0.x,a0, fmaf(r0.y,a1, fmaf(r0.z,a2, fmaf(r0.w,a3, fmaf(r1.x,a4, r1.y*a5))))) + qd.x + ab;
    float sc1 = fmaf(r1.z,a0, fmaf(r1.w,a1, fmaf(r2.x,a2, fmaf(r2.y,a3, fmaf(r2.z,a4, r2.w*a5))))) + qd.y + ab;
    float sc2 = fmaf(r3.x,a0, fmaf(r3.y,a1, fmaf(r3.z,a2, fmaf(r3.w,a3, fmaf(r4.x,a4, r4.y*a5))))) + qd.z + ab;
    float m0 = sc0, m1 = sc1, m2 = sc2;
#pragma unroll
    for (int off = 16; off > 0; off >>= 1) {
        m0 = fmaxf(m0, __shfl_xor(m0, off, 32));
        m1 = fmaxf(m1, __shfl_xor(m1, off, 32));
        m2 = fmaxf(m2, __shfl_xor(m2, off, 32));
    }
    float w0 = __expf(sc0 - m0), w1 = __expf(sc1 - m1), w2 = __expf(sc2 - m2);
    float l0 = w0, l1 = w1, l2 = w2;
    float v[18];
    v[0]=w0*r0.x; v[1]=w0*r0.y; v[2]=w0*r0.z; v[3]=w0*r0.w; v[4]=w0*r1.x; v[5]=w0*r1.y;
    v[6]=w1*r1.z; v[7]=w1*r1.w; v[8]=w1*r2.x; v[9]=w1*r2.y; v[10]=w1*r2.z; v[11]=w1*r2.w;
    v[12]=w2*r3.x; v[13]=w2*r3.y; v[14]=w2*r3.z; v[15]=w2*r3.w; v[16]=w2*r4.x; v[17]=w2*r4.y;
#pragma unroll
    for (int off = 16; off > 0; off >>= 1) {
        l0 += __shfl_xor(l0, off, 32);
        l1 += __shfl_xor(l1, off, 32);
        l2 += __shfl_xor(l2, off, 32);
#pragma unroll
        for (int j = 0; j < 18; ++j) v[j] += __shfl_xor(v[j], off, 32);
    }
    __shared__ float so[8][18];
    if (k == 0) {
        float i0 = 1.f / (l0 * (float)KN);
        float i1 = 1.f / (l1 * (float)KN);
        float i2 = 1.f / (l2 * (float)KN);
        size_t base = (size_t)node * 18;
#pragma unroll
        for (int j = 0; j < 6; ++j) {
            float o0 = v[j] * i0, o1 = v[6 + j] * i1, o2 = v[12 + j] * i2;
            out[base + j] = o0;      so[hw][j] = o0;
            out[base + 6 + j] = o1;  so[hw][6 + j] = o1;
            out[base + 12 + j] = o2; so[hw][12 + j] = o2;
        }
    }
    __syncthreads();
    if (threadIdx.x < 18) {
        int t = threadIdx.x;
        float ps = 0.f, pss = 0.f;
#pragma unroll
        for (int h = 0; h < 8; ++h) { float vv = so[h][t]; ps += vv; pss = fmaf(vv, vv, pss); }
        int slot = (blockIdx.x & (NSLOT - 1)) * 36;
        atomicAdd(&slots[slot + t], ps);
        atomicAdd(&slots[slot + 18 + t], pss);
    }
}

// ---------------- prep2: reduce slots, fold BN1+BN2 into M2 (22x18) + c2 ----------------
__global__ void prep2_kernel(const float* __restrict__ SS, const float* __restrict__ X2S,
                             float* __restrict__ P,
                             const float* W0, const float* g1, const float* be1,
                             const float* g2, const float* be2,
                             const float* W2, const float* b2) {
    __shared__ float muS[3], varS[3], alpha[18], beta[18], gam[18], del[18];
    int t = threadIdx.x;
    if (t < 3) {
        float s = 0.f, ss = 0.f;
#pragma unroll 8
        for (int i = 0; i < NSLOT; ++i) { s += SS[i * 8 + t]; ss += SS[i * 8 + 4 + t]; }
        float mu = s / (float)N_NODES;
        muS[t] = mu; varS[t] = ss / (float)N_NODES - mu * mu;
    }
    if (t < 18) {
        float s = 0.f, ss = 0.f;
#pragma unroll 8
        for (int i = 0; i < NSLOT; ++i) { s += X2S[i * 36 + t]; ss += X2S[i * 36 + 18 + t]; }
        float mu2 = s / (float)N_NODES;
        float var2 = ss / (float)N_NODES - mu2 * mu2;
        float g = rsqrtf(var2 + EPS) * g2[t];
        gam[t] = g; del[t] = be2[t] - mu2 * g;
    }
    __syncthreads();
    if (t < 18) {
        int h = t / 6;
        float w = W0[t] / (float)KN;
        float inv1 = rsqrtf(varS[h] * w * w + EPS);
        float gg = inv1 * g1[t];
        alpha[t] = w * gg;
        beta[t]  = be1[t] - w * gg * muS[h];
    }
    __syncthreads();
    if (t < 18) {
        int j = t;
        float* M2 = P + 112; float* c2 = P + 508;
        M2[j] = W2[j];
        for (int h = 0; h < 3; ++h) {
            float acc = 0.f;
            for (int f = 0; f < 6; ++f) acc = fmaf(alpha[h * 6 + f], W2[(1 + h * 6 + f) * 18 + j], acc);
            M2[(1 + h) * 18 + j] = acc;
        }
        for (int c = 0; c < 18; ++c) M2[(4 + c) * 18 + j] = gam[c] * W2[(19 + c) * 18 + j];
        float cc = b2[j];
        for (int c = 0; c < 18; ++c) cc = fmaf(beta[c], W2[(1 + c) * 18 + j], cc);
        for (int c = 0; c < 18; ++c) cc = fmaf(del[c],  W2[(19 + c) * 18 + j], cc);
        c2[j] = cc;
    }
}

// ---------------- xe2 = [x0,S,x2raw] @ M2 + c2 ; q2 ----------------
__global__ void xe2_kernel(const float* __restrict__ x0, const float4* __restrict__ S4,
                           const float* __restrict__ x2, const float* __restrict__ P,
                           const float* __restrict__ aW2,
                           float* __restrict__ xe, float4* __restrict__ q4) {
    int n = blockIdx.x * blockDim.x + threadIdx.x;
    if (n >= N_NODES) return;
    float xv = x0[n];
    float4 S = S4[n];
    float xr[18];
    const float2* x2p = (const float2*)(x2 + (size_t)n * 18);
#pragma unroll
    for (int q = 0; q < 9; ++q) { float2 v = x2p[q]; xr[2 * q] = v.x; xr[2 * q + 1] = v.y; }
    const float* M2 = P + 112; const float* c2 = P + 508;
    float row[18];
#pragma unroll
    for (int j = 0; j < 18; ++j) {
        float r = c2[j];
        r = fmaf(xv,  M2[j],      r);
        r = fmaf(S.x, M2[18 + j], r);
        r = fmaf(S.y, M2[36 + j], r);
        r = fmaf(S.z, M2[54 + j], r);
#pragma unroll
        for (int c = 0; c < 18; ++c) r = fmaf(xr[c], M2[(4 + c) * 18 + j], r);
        row[j] = r;
    }
    float4* xp = (float4*)(xe + (size_t)n * 20);
    xp[0] = make_float4(row[0], row[1], row[2], row[3]);
    xp[1] = make_float4(row[4], row[5], row[6], row[7]);
    xp[2] = make_float4(row[8], row[9], row[10], row[11]);
    xp[3] = make_float4(row[12], row[13], row[14], row[15]);
    *(float2*)(xe + (size_t)n * 20 + 16) = make_float2(row[16], row[17]);
    float q0 = 0.f, q1 = 0.f, q2 = 0.f;
#pragma unroll
    for (int f = 0; f < 6; ++f) {
        float a = aW2[6 + f];
        q0 = fmaf(row[f], a, q0);
        q1 = fmaf(row[6 + f], a, q1);
        q2 = fmaf(row[12 + f], a, q2);
    }
    q4[n] = make_float4(q0, q1, q2, 0.f);
}

// ---------------- prepF: reduce Y slots, fold BN3 into final dot ----------------
__global__ void prepF_kernel(const float* __restrict__ YS, float* __restrict__ P,
                             const float* g3, const float* be3,
                             const float* fW, const float* fb) {
    __shared__ float part[18];
    int t = threadIdx.x;
    if (t < 18) {
        float s = 0.f, ss = 0.f;
#pragma unroll 8
        for (int i = 0; i < NSLOT; ++i) { s += YS[i * 36 + t]; ss += YS[i * 36 + 18 + t]; }
        float mu = s / (float)N_NODES;
        float var = ss / (float)N_NODES - mu * mu;
        float g = rsqrtf(var + EPS) * g3[t];
        P[528 + t] = g * fW[t];
        part[t] = (be3[t] - mu * g) * fW[t];
    }
    __syncthreads();
    if (t == 0) {
        float cf = fb[0];
        for (int j = 0; j < 18; ++j) cf += part[j];
        P[546] = cf;
    }
}

// ---------------- final: out = y @ wf + cf (2 nodes/thread, float4 loads) ----------------
__global__ __launch_bounds__(256)
void final_kernel(const float4* __restrict__ y4, const float* __restrict__ P,
                  float2* __restrict__ out2) {
    int i = blockIdx.x * blockDim.x + threadIdx.x;
    if (i >= 50000) return;
    const float4* yp = y4 + (size_t)i * 9;
    float a[36];
#pragma unroll
    for (int q = 0; q < 9; ++q) {
        float4 v = yp[q];
        a[4 * q] = v.x; a[4 * q + 1] = v.y; a[4 * q + 2] = v.z; a[4 * q + 3] = v.w;
    }
    float cf = P[546];
    float acc0 = cf, acc1 = cf;
#pragma unroll
    for (int j = 0; j < 18; ++j) {
        float w = P[528 + j];
        acc0 = fmaf(a[j], w, acc0);
        acc1 = fmaf(a[18 + j], w, acc1);
    }
    out2[i] = make_float2(acc0, acc1);
}

extern "C" void kernel_launch(void* const* d_in, const int* in_sizes, int n_in,
                              void* d_out, int out_size, void* d_ws, size_t ws_size,
                              hipStream_t stream) {
    const float* x   = (const float*)d_in[0];
    const int*   ei  = (const int*)d_in[1];
    const float* e   = (const float*)d_in[2];
    const float* W0  = (const float*)d_in[3];
    const float* b0  = (const float*)d_in[4];
    const float* aW0 = (const float*)d_in[5];
    const float* ab0 = (const float*)d_in[6];
    const float* W1  = (const float*)d_in[7];
    const float* b1  = (const float*)d_in[8];
    const float* aW1 = (const float*)d_in[9];
    const float* ab1 = (const float*)d_in[10];
    const float* W2  = (const float*)d_in[11];
    const float* b2  = (const float*)d_in[12];
    const float* aW2 = (const float*)d_in[13];
    const float* ab2 = (const float*)d_in[14];
    const float* g0  = (const float*)d_in[15];
    const float* be0 = (const float*)d_in[16];
    const float* g1  = (const float*)d_in[17];
    const float* be1 = (const float*)d_in[18];
    const float* g2  = (const float*)d_in[19];
    const float* be2 = (const float*)d_in[20];
    const float* g3  = (const float*)d_in[21];
    const float* be3 = (const float*)d_in[22];
    const float* fW  = (const float*)d_in[23];
    const float* fb  = (const float*)d_in[24];

    const int* ei0 = ei;
    const int* ei1 = ei + (size_t)N_NODES * KN;

    float*  ws  = (float*)d_ws;
    float*  x0  = ws + OFF_X0;
    float4* S4  = (float4*)(ws + OFF_S4);
    float*  xe  = ws + OFF_XE;
    float4* q4  = (float4*)(ws + OFF_Q4);
    float*  x2  = ws + OFF_X2;
    float*  y   = ws + OFF_Y;
    float*  TX  = ws + OFF_TX;
    float*  SS  = ws + OFF_SS;
    float*  X2S = ws + OFF_X2S;
    float*  YS  = ws + OFF_YS;
    float*  P   = ws + OFF_P;

    // zero all stats accumulators (TX..P region)
    hipMemsetAsync(TX, 0, (OFF_P - OFF_TX) * sizeof(float), stream);

    // stage 0: BN0
    statsx_kernel<<<98, 256, 0, stream>>>((const float4*)x, TX);
    prep0_kernel<<<1, 1, 0, stream>>>(TX, P, g0, be0, W0, b0, aW0, ab0);
    x0_kernel<<<98, 256, 0, stream>>>((const float4*)x, P, (float4*)x0);

    // layer 0 (rank-1): S per node, fused S stats
    att0_kernel<<<N_NODES / 8, 256, 0, stream>>>(x0, ei0, ei1, (const float2*)e, P, S4, SS);

    // layer 1
    prep1_kernel<<<1, 64, 0, stream>>>(SS, P, W0, g1, be1, W1, b1);
    xe1_kernel<<<(N_NODES + 255) / 256, 256, 0, stream>>>(x0, S4, P, aW1, xe, q4);
    att_big_kernel<<<N_NODES / 8, 256, 0, stream>>>(xe, q4, ei0, ei1, aW1, ab1, x2, X2S);

    // layer 2
    prep2_kernel<<<1, 64, 0, stream>>>(SS, X2S, P, W0, g1, be1, g2, be2, W2, b2);
    xe2_kernel<<<(N_NODES + 255) / 256, 256, 0, stream>>>(x0, S4, x2, P, aW2, xe, q4);
    att_big_kernel<<<N_NODES / 8, 256, 0, stream>>>(xe, q4, ei0, ei1, aW2, ab2, y, YS);

    // final BN3 + fc
    prepF_kernel<<<1, 64, 0, stream>>>(YS, P, g3, be3, fW, fb);
    final_kernel<<<(50000 + 255) / 256, 256, 0, stream>>>((const float4*)y, P, (float2*)d_out);
}

// Round 10
// 348.571 us; speedup vs baseline: 1.8440x; 1.0557x over previous
//
#include <hip/hip_runtime.h>
#include <hip/hip_fp16.h>

#define N_NODES 100000
#define KN 32
#define EPS 1e-5f
#define NSLOT 128

// ---------------- workspace layout (float offsets) ----------------
#define OFF_X0   0          // [100000]   normalized scalar input
#define OFF_XEH  500000     // [100000*24 ushorts = 4.8MB] packed fp16 rows: 18 xe, pad, pad, 3 q, pad
#define OFF_S4   2500000    // [100000*4] layer0 per-head weighted sums (float4)
#define OFF_X2   2900000    // [100000*18] layer1 raw output (fp32)
#define OFF_Y    4700000    // [100000*18] layer2 raw output (fp32)
#define OFF_TX   6500000    // [16]   x sum/ss
#define OFF_SS   6500016    // [128*8]  S slotted stats
#define OFF_X2S  6501040    // [128*36] x2 slotted stats
#define OFF_YS   6505648    // [128*36] y slotted stats
#define OFF_P    6510256    // [1024] derived params
// params in P: 0 s0, 1 t0 | 2..4 A | 5..7 B | 8..10 C | 11 ew0, 12 ew1
//              16..87 M1(4x18), 88..105 c1 | 112..507 M2(22x18), 508..525 c2 | 528..545 wf, 546 cf

__device__ inline float2 h2f2(unsigned int w) {
    __half2 h = *reinterpret_cast<__half2*>(&w);
    return __half22float2(h);
}

// ---------------- stats of scalar input x (vectorized) ----------------
__global__ __launch_bounds__(256)
void statsx_kernel(const float4* __restrict__ x4, float* __restrict__ acc) {
    int i = blockIdx.x * 256 + threadIdx.x;
    float s = 0.f, ss = 0.f;
    if (i < 25000) {
        float4 v = x4[i];
        s = v.x + v.y + v.z + v.w;
        ss = v.x * v.x + v.y * v.y + v.z * v.z + v.w * v.w;
    }
#pragma unroll
    for (int off = 32; off > 0; off >>= 1) {
        s  += __shfl_xor(s,  off, 64);
        ss += __shfl_xor(ss, off, 64);
    }
    __shared__ float ls[4], lss[4];
    int wid = threadIdx.x >> 6;
    if ((threadIdx.x & 63) == 0) { ls[wid] = s; lss[wid] = ss; }
    __syncthreads();
    if (threadIdx.x == 0) {
        atomicAdd(&acc[0], ls[0] + ls[1] + ls[2] + ls[3]);
        atomicAdd(&acc[1], lss[0] + lss[1] + lss[2] + lss[3]);
    }
}

// ---------------- prep0: BN0 fold + layer0 score constants ----------------
__global__ void prep0_kernel(const float* __restrict__ T, float* __restrict__ P,
                             const float* g0, const float* be0,
                             const float* W0, const float* b0,
                             const float* aW0, const float* ab0) {
    if (threadIdx.x || blockIdx.x) return;
    float mu  = T[0] / (float)N_NODES;
    float var = T[1] / (float)N_NODES - mu * mu;
    float inv = rsqrtf(var + EPS);
    float s0 = inv * g0[0];
    P[0] = s0; P[1] = be0[0] - mu * s0;
    for (int h = 0; h < 3; ++h) {
        float A = 0.f, B = 0.f, Cc = 0.f;
        for (int f = 0; f < 6; ++f) {
            A  = fmaf(W0[h * 6 + f], aW0[f], A);
            B  = fmaf(W0[h * 6 + f], aW0[6 + f], B);
            Cc = fmaf(b0[h * 6 + f], aW0[f] + aW0[6 + f], Cc);
        }
        P[2 + h] = A; P[5 + h] = B; P[8 + h] = Cc + ab0[0];
    }
    P[11] = aW0[12]; P[12] = aW0[13];
}

// ---------------- x0 = BN0(x), vectorized ----------------
__global__ void x0_kernel(const float4* __restrict__ x4, const float* __restrict__ P,
                          float4* __restrict__ x0) {
    int i = blockIdx.x * blockDim.x + threadIdx.x;
    if (i < 25000) {
        float4 v = x4[i];
        float s = P[0], t = P[1];
        x0[i] = make_float4(fmaf(v.x, s, t), fmaf(v.y, s, t), fmaf(v.z, s, t), fmaf(v.w, s, t));
    }
}

// ---------------- layer0 attention + fused S stats ----------------
__global__ __launch_bounds__(256)
void att0_kernel(const float* __restrict__ x0,
                 const int* __restrict__ ei0, const int* __restrict__ ei1,
                 const float2* __restrict__ e2,
                 const float* __restrict__ P, float4* __restrict__ S4,
                 float* __restrict__ SS) {
    int hw = threadIdx.x >> 5;
    int node = blockIdx.x * 8 + hw;          // grid is exactly N/8 blocks
    int k = threadIdx.x & 31;
    int eidx = node * KN + k;
    int s = ei0[eidx], d = ei1[eidx];
    float xs = x0[s], xd = x0[d];
    float2 ef = e2[eidx];
    float eb = fmaf(ef.x, P[11], ef.y * P[12]);
    float sc0 = fmaf(xs, P[2], fmaf(xd, P[5], P[8]  + eb));
    float sc1 = fmaf(xs, P[3], fmaf(xd, P[6], P[9]  + eb));
    float sc2 = fmaf(xs, P[4], fmaf(xd, P[7], P[10] + eb));
    float m0 = sc0, m1 = sc1, m2 = sc2;
#pragma unroll
    for (int off = 16; off > 0; off >>= 1) {
        m0 = fmaxf(m0, __shfl_xor(m0, off, 32));
        m1 = fmaxf(m1, __shfl_xor(m1, off, 32));
        m2 = fmaxf(m2, __shfl_xor(m2, off, 32));
    }
    float w0 = __expf(sc0 - m0), w1 = __expf(sc1 - m1), w2 = __expf(sc2 - m2);
    float l0 = w0, l1 = w1, l2 = w2;
    float a0 = w0 * xs, a1 = w1 * xs, a2 = w2 * xs;
#pragma unroll
    for (int off = 16; off > 0; off >>= 1) {
        l0 += __shfl_xor(l0, off, 32); a0 += __shfl_xor(a0, off, 32);
        l1 += __shfl_xor(l1, off, 32); a1 += __shfl_xor(a1, off, 32);
        l2 += __shfl_xor(l2, off, 32); a2 += __shfl_xor(a2, off, 32);
    }
    __shared__ float sS[8][4];
    if (k == 0) {
        float v0 = a0 / l0, v1 = a1 / l1, v2 = a2 / l2;
        S4[node] = make_float4(v0, v1, v2, 0.f);
        sS[hw][0] = v0; sS[hw][1] = v1; sS[hw][2] = v2;
    }
    __syncthreads();
    if (threadIdx.x < 3) {
        float ps = 0.f, pss = 0.f;
#pragma unroll
        for (int h = 0; h < 8; ++h) { float v = sS[h][threadIdx.x]; ps += v; pss = fmaf(v, v, pss); }
        int slot = (blockIdx.x & (NSLOT - 1)) * 8;
        atomicAdd(&SS[slot + threadIdx.x], ps);
        atomicAdd(&SS[slot + 4 + threadIdx.x], pss);
    }
}

// ---------------- prep1: reduce S slots, fold BN1 into M1 (4x18) + c1 ----------------
__global__ void prep1_kernel(const float* __restrict__ SS, float* __restrict__ P,
                             const float* W0, const float* g1, const float* be1,
                             const float* W1, const float* b1) {
    __shared__ float muS[3], varS[3], alpha[18], beta[18];
    int t = threadIdx.x;
    if (t < 3) {
        float s = 0.f, ss = 0.f;
#pragma unroll 8
        for (int i = 0; i < NSLOT; ++i) { s += SS[i * 8 + t]; ss += SS[i * 8 + 4 + t]; }
        float mu = s / (float)N_NODES;
        muS[t] = mu; varS[t] = ss / (float)N_NODES - mu * mu;
    }
    __syncthreads();
    if (t < 18) {
        int h = t / 6;
        float w = W0[t] / (float)KN;
        float inv1 = rsqrtf(varS[h] * w * w + EPS);
        float gg = inv1 * g1[t];
        alpha[t] = w * gg;
        beta[t]  = be1[t] - w * gg * muS[h];
    }
    __syncthreads();
    if (t < 18) {
        int j = t;
        float* M1 = P + 16; float* c1 = P + 88;
        M1[j] = W1[j];
        for (int h = 0; h < 3; ++h) {
            float acc = 0.f;
            for (int f = 0; f < 6; ++f) acc = fmaf(alpha[h * 6 + f], W1[(1 + h * 6 + f) * 18 + j], acc);
            M1[(1 + h) * 18 + j] = acc;
        }
        float cc = b1[j];
        for (int c = 0; c < 18; ++c) cc = fmaf(beta[c], W1[(1 + c) * 18 + j], cc);
        c1[j] = cc;
    }
}

// ---------------- pack row[18] + q[3] into 24 fp16 (48B) ----------------
__device__ inline void pack_row(unsigned short* __restrict__ xeh, int n,
                                const float* row, float q0, float q1, float q2) {
    union { unsigned short u[24]; uint4 v[3]; } pk;
#pragma unroll
    for (int j = 0; j < 18; ++j) pk.u[j] = __half_as_ushort(__float2half(row[j]));
    pk.u[18] = 0; pk.u[19] = 0;
    pk.u[20] = __half_as_ushort(__float2half(q0));
    pk.u[21] = __half_as_ushort(__float2half(q1));
    pk.u[22] = __half_as_ushort(__float2half(q2));
    pk.u[23] = 0;
    uint4* dst = (uint4*)(xeh + (size_t)n * 24);
    dst[0] = pk.v[0]; dst[1] = pk.v[1]; dst[2] = pk.v[2];
}

// ---------------- xe1 = [x0,S] @ M1 + c1 ; pack fp16 row+q ----------------
__global__ void xe1_kernel(const float* __restrict__ x0, const float4* __restrict__ S4,
                           const float* __restrict__ P, const float* __restrict__ aW1,
                           unsigned short* __restrict__ xeh) {
    int n = blockIdx.x * blockDim.x + threadIdx.x;
    if (n >= N_NODES) return;
    float xv = x0[n];
    float4 S = S4[n];
    const float* M1 = P + 16; const float* c1 = P + 88;
    float row[18];
#pragma unroll
    for (int j = 0; j < 18; ++j) {
        float r = c1[j];
        r = fmaf(xv,  M1[j],      r);
        r = fmaf(S.x, M1[18 + j], r);
        r = fmaf(S.y, M1[36 + j], r);
        r = fmaf(S.z, M1[54 + j], r);
        row[j] = r;
    }
    float q0 = 0.f, q1 = 0.f, q2 = 0.f;
#pragma unroll
    for (int f = 0; f < 6; ++f) {
        float a = aW1[6 + f];
        q0 = fmaf(row[f], a, q0);
        q1 = fmaf(row[6 + f], a, q1);
        q2 = fmaf(row[12 + f], a, q2);
    }
    pack_row(xeh, n, row, q0, q1, q2);
}

// ---------------- big attention (layers 1 & 2), fp16 gathers + fused channel stats ----------------
__global__ __launch_bounds__(256)
void att_big_kernel(const unsigned short* __restrict__ xeh,
                    const int* __restrict__ ei0, const int* __restrict__ ei1,
                    const float* __restrict__ aW, const float* __restrict__ abp,
                    float* __restrict__ out, float* __restrict__ slots) {
    int hw = threadIdx.x >> 5;
    int node = blockIdx.x * 8 + hw;          // grid exactly N/8
    int k = threadIdx.x & 31;
    int eidx = node * KN + k;
    int s = ei0[eidx], d = ei1[eidx];
    const unsigned short* rs = xeh + (size_t)s * 24;
    uint4 A = *(const uint4*)rs;                 // halves 0..7
    uint4 B = *(const uint4*)(rs + 8);           // halves 8..15
    unsigned int C = *(const unsigned int*)(rs + 16);  // halves 16,17
    uint2 Q = *(const uint2*)(xeh + (size_t)d * 24 + 20); // halves 20..23 (q0,q1,q2,pad)
    float2 p01 = h2f2(A.x), p23 = h2f2(A.y), p45 = h2f2(A.z), p67 = h2f2(A.w);
    float2 p89 = h2f2(B.x), pab = h2f2(B.y), pcd = h2f2(B.z), pef = h2f2(B.w);
    float2 pgh = h2f2(C);
    float2 q01 = h2f2(Q.x), q2_ = h2f2(Q.y);
    float r[18];
    r[0]=p01.x; r[1]=p01.y; r[2]=p23.x; r[3]=p23.y; r[4]=p45.x; r[5]=p45.y;
    r[6]=p67.x; r[7]=p67.y; r[8]=p89.x; r[9]=p89.y; r[10]=pab.x; r[11]=pab.y;
    r[12]=pcd.x; r[13]=pcd.y; r[14]=pef.x; r[15]=pef.y; r[16]=pgh.x; r[17]=pgh.y;
    float a0 = aW[0], a1 = aW[1], a2 = aW[2], a3 = aW[3], a4 = aW[4], a5 = aW[5];
    float ab = abp[0];
    float sc0 = fmaf(r[0],a0, fmaf(r[1],a1, fmaf(r[2],a2, fmaf(r[3],a3, fmaf(r[4],a4, r[5]*a5))))) + q01.x + ab;
    float sc1 = fmaf(r[6],a0, fmaf(r[7],a1, fmaf(r[8],a2, fmaf(r[9],a3, fmaf(r[10],a4, r[11]*a5))))) + q01.y + ab;
    float sc2 = fmaf(r[12],a0, fmaf(r[13],a1, fmaf(r[14],a2, fmaf(r[15],a3, fmaf(r[16],a4, r[17]*a5))))) + q2_.x + ab;
    float m0 = sc0, m1 = sc1, m2 = sc2;
#pragma unroll
    for (int off = 16; off > 0; off >>= 1) {
        m0 = fmaxf(m0, __shfl_xor(m0, off, 32));
        m1 = fmaxf(m1, __shfl_xor(m1, off, 32));
        m2 = fmaxf(m2, __shfl_xor(m2, off, 32));
    }
    float w0 = __expf(sc0 - m0), w1 = __expf(sc1 - m1), w2 = __expf(sc2 - m2);
    float l0 = w0, l1 = w1, l2 = w2;
    float v[18];
#pragma unroll
    for (int j = 0; j < 6; ++j) {
        v[j]      = w0 * r[j];
        v[6 + j]  = w1 * r[6 + j];
        v[12 + j] = w2 * r[12 + j];
    }
#pragma unroll
    for (int off = 16; off > 0; off >>= 1) {
        l0 += __shfl_xor(l0, off, 32);
        l1 += __shfl_xor(l1, off, 32);
        l2 += __shfl_xor(l2, off, 32);
#pragma unroll
        for (int j = 0; j < 18; ++j) v[j] += __shfl_xor(v[j], off, 32);
    }
    __shared__ float so[8][18];
    if (k == 0) {
        float i0 = 1.f / (l0 * (float)KN);
        float i1 = 1.f / (l1 * (float)KN);
        float i2 = 1.f / (l2 * (float)KN);
        size_t base = (size_t)node * 18;
#pragma unroll
        for (int j = 0; j < 6; ++j) {
            float o0 = v[j] * i0, o1 = v[6 + j] * i1, o2 = v[12 + j] * i2;
            out[base + j] = o0;      so[hw][j] = o0;
            out[base + 6 + j] = o1;  so[hw][6 + j] = o1;
            out[base + 12 + j] = o2; so[hw][12 + j] = o2;
        }
    }
    __syncthreads();
    if (threadIdx.x < 18) {
        int t = threadIdx.x;
        float ps = 0.f, pss = 0.f;
#pragma unroll
        for (int h = 0; h < 8; ++h) { float vv = so[h][t]; ps += vv; pss = fmaf(vv, vv, pss); }
        int slot = (blockIdx.x & (NSLOT - 1)) * 36;
        atomicAdd(&slots[slot + t], ps);
        atomicAdd(&slots[slot + 18 + t], pss);
    }
}

// ---------------- prep2: reduce slots, fold BN1+BN2 into M2 (22x18) + c2 ----------------
__global__ void prep2_kernel(const float* __restrict__ SS, const float* __restrict__ X2S,
                             float* __restrict__ P,
                             const float* W0, const float* g1, const float* be1,
                             const float* g2, const float* be2,
                             const float* W2, const float* b2) {
    __shared__ float muS[3], varS[3], alpha[18], beta[18], gam[18], del[18];
    int t = threadIdx.x;
    if (t < 3) {
        float s = 0.f, ss = 0.f;
#pragma unroll 8
        for (int i = 0; i < NSLOT; ++i) { s += SS[i * 8 + t]; ss += SS[i * 8 + 4 + t]; }
        float mu = s / (float)N_NODES;
        muS[t] = mu; varS[t] = ss / (float)N_NODES - mu * mu;
    }
    if (t < 18) {
        float s = 0.f, ss = 0.f;
#pragma unroll 8
        for (int i = 0; i < NSLOT; ++i) { s += X2S[i * 36 + t]; ss += X2S[i * 36 + 18 + t]; }
        float mu2 = s / (float)N_NODES;
        float var2 = ss / (float)N_NODES - mu2 * mu2;
        float g = rsqrtf(var2 + EPS) * g2[t];
        gam[t] = g; del[t] = be2[t] - mu2 * g;
    }
    __syncthreads();
    if (t < 18) {
        int h = t / 6;
        float w = W0[t] / (float)KN;
        float inv1 = rsqrtf(varS[h] * w * w + EPS);
        float gg = inv1 * g1[t];
        alpha[t] = w * gg;
        beta[t]  = be1[t] - w * gg * muS[h];
    }
    __syncthreads();
    if (t < 18) {
        int j = t;
        float* M2 = P + 112; float* c2 = P + 508;
        M2[j] = W2[j];
        for (int h = 0; h < 3; ++h) {
            float acc = 0.f;
            for (int f = 0; f < 6; ++f) acc = fmaf(alpha[h * 6 + f], W2[(1 + h * 6 + f) * 18 + j], acc);
            M2[(1 + h) * 18 + j] = acc;
        }
        for (int c = 0; c < 18; ++c) M2[(4 + c) * 18 + j] = gam[c] * W2[(19 + c) * 18 + j];
        float cc = b2[j];
        for (int c = 0; c < 18; ++c) cc = fmaf(beta[c], W2[(1 + c) * 18 + j], cc);
        for (int c = 0; c < 18; ++c) cc = fmaf(del[c],  W2[(19 + c) * 18 + j], cc);
        c2[j] = cc;
    }
}

// ---------------- xe2 = [x0,S,x2raw] @ M2 + c2 ; pack fp16 row+q ----------------
__global__ void xe2_kernel(const float* __restrict__ x0, const float4* __restrict__ S4,
                           const float* __restrict__ x2, const float* __restrict__ P,
                           const float* __restrict__ aW2,
                           unsigned short* __restrict__ xeh) {
    int n = blockIdx.x * blockDim.x + threadIdx.x;
    if (n >= N_NODES) return;
    float xv = x0[n];
    float4 S = S4[n];
    float xr[18];
    const float2* x2p = (const float2*)(x2 + (size_t)n * 18);
#pragma unroll
    for (int q = 0; q < 9; ++q) { float2 v = x2p[q]; xr[2 * q] = v.x; xr[2 * q + 1] = v.y; }
    const float* M2 = P + 112; const float* c2 = P + 508;
    float row[18];
#pragma unroll
    for (int j = 0; j < 18; ++j) {
        float r = c2[j];
        r = fmaf(xv,  M2[j],      r);
        r = fmaf(S.x, M2[18 + j], r);
        r = fmaf(S.y, M2[36 + j], r);
        r = fmaf(S.z, M2[54 + j], r);
#pragma unroll
        for (int c = 0; c < 18; ++c) r = fmaf(xr[c], M2[(4 + c) * 18 + j], r);
        row[j] = r;
    }
    float q0 = 0.f, q1 = 0.f, q2 = 0.f;
#pragma unroll
    for (int f = 0; f < 6; ++f) {
        float a = aW2[6 + f];
        q0 = fmaf(row[f], a, q0);
        q1 = fmaf(row[6 + f], a, q1);
        q2 = fmaf(row[12 + f], a, q2);
    }
    pack_row(xeh, n, row, q0, q1, q2);
}

// ---------------- prepF: reduce Y slots, fold BN3 into final dot ----------------
__global__ void prepF_kernel(const float* __restrict__ YS, float* __restrict__ P,
                             const float* g3, const float* be3,
                             const float* fW, const float* fb) {
    __shared__ float part[18];
    int t = threadIdx.x;
    if (t < 18) {
        float s = 0.f, ss = 0.f;
#pragma unroll 8
        for (int i = 0; i < NSLOT; ++i) { s += YS[i * 36 + t]; ss += YS[i * 36 + 18 + t]; }
        float mu = s / (float)N_NODES;
        float var = ss / (float)N_NODES - mu * mu;
        float g = rsqrtf(var + EPS) * g3[t];
        P[528 + t] = g * fW[t];
        part[t] = (be3[t] - mu * g) * fW[t];
    }
    __syncthreads();
    if (t == 0) {
        float cf = fb[0];
        for (int j = 0; j < 18; ++j) cf += part[j];
        P[546] = cf;
    }
}

// ---------------- final: out = y @ wf + cf (2 nodes/thread, float4 loads) ----------------
__global__ __launch_bounds__(256)
void final_kernel(const float4* __restrict__ y4, const float* __restrict__ P,
                  float2* __restrict__ out2) {
    int i = blockIdx.x * blockDim.x + threadIdx.x;
    if (i >= 50000) return;
    const float4* yp = y4 + (size_t)i * 9;
    float a[36];
#pragma unroll
    for (int q = 0; q < 9; ++q) {
        float4 v = yp[q];
        a[4 * q] = v.x; a[4 * q + 1] = v.y; a[4 * q + 2] = v.z; a[4 * q + 3] = v.w;
    }
    float cf = P[546];
    float acc0 = cf, acc1 = cf;
#pragma unroll
    for (int j = 0; j < 18; ++j) {
        float w = P[528 + j];
        acc0 = fmaf(a[j], w, acc0);
        acc1 = fmaf(a[18 + j], w, acc1);
    }
    out2[i] = make_float2(acc0, acc1);
}

extern "C" void kernel_launch(void* const* d_in, const int* in_sizes, int n_in,
                              void* d_out, int out_size, void* d_ws, size_t ws_size,
                              hipStream_t stream) {
    const float* x   = (const float*)d_in[0];
    const int*   ei  = (const int*)d_in[1];
    const float* e   = (const float*)d_in[2];
    const float* W0  = (const float*)d_in[3];
    const float* b0  = (const float*)d_in[4];
    const float* aW0 = (const float*)d_in[5];
    const float* ab0 = (const float*)d_in[6];
    const float* W1  = (const float*)d_in[7];
    const float* b1  = (const float*)d_in[8];
    const float* aW1 = (const float*)d_in[9];
    const float* ab1 = (const float*)d_in[10];
    const float* W2  = (const float*)d_in[11];
    const float* b2  = (const float*)d_in[12];
    const float* aW2 = (const float*)d_in[13];
    const float* ab2 = (const float*)d_in[14];
    const float* g0  = (const float*)d_in[15];
    const float* be0 = (const float*)d_in[16];
    const float* g1  = (const float*)d_in[17];
    const float* be1 = (const float*)d_in[18];
    const float* g2  = (const float*)d_in[19];
    const float* be2 = (const float*)d_in[20];
    const float* g3  = (const float*)d_in[21];
    const float* be3 = (const float*)d_in[22];
    const float* fW  = (const float*)d_in[23];
    const float* fb  = (const float*)d_in[24];

    const int* ei0 = ei;
    const int* ei1 = ei + (size_t)N_NODES * KN;

    float*  ws  = (float*)d_ws;
    float*  x0  = ws + OFF_X0;
    unsigned short* xeh = (unsigned short*)(ws + OFF_XEH);
    float4* S4  = (float4*)(ws + OFF_S4);
    float*  x2  = ws + OFF_X2;
    float*  y   = ws + OFF_Y;
    float*  TX  = ws + OFF_TX;
    float*  SS  = ws + OFF_SS;
    float*  X2S = ws + OFF_X2S;
    float*  YS  = ws + OFF_YS;
    float*  P   = ws + OFF_P;

    // zero all stats accumulators (TX..P region)
    hipMemsetAsync(TX, 0, (OFF_P - OFF_TX) * sizeof(float), stream);

    // stage 0: BN0
    statsx_kernel<<<98, 256, 0, stream>>>((const float4*)x, TX);
    prep0_kernel<<<1, 1, 0, stream>>>(TX, P, g0, be0, W0, b0, aW0, ab0);
    x0_kernel<<<98, 256, 0, stream>>>((const float4*)x, P, (float4*)x0);

    // layer 0 (rank-1): S per node, fused S stats
    att0_kernel<<<N_NODES / 8, 256, 0, stream>>>(x0, ei0, ei1, (const float2*)e, P, S4, SS);

    // layer 1
    prep1_kernel<<<1, 64, 0, stream>>>(SS, P, W0, g1, be1, W1, b1);
    xe1_kernel<<<(N_NODES + 255) / 256, 256, 0, stream>>>(x0, S4, P, aW1, xeh);
    att_big_kernel<<<N_NODES / 8, 256, 0, stream>>>(xeh, ei0, ei1, aW1, ab1, x2, X2S);

    // layer 2
    prep2_kernel<<<1, 64, 0, stream>>>(SS, X2S, P, W0, g1, be1, g2, be2, W2, b2);
    xe2_kernel<<<(N_NODES + 255) / 256, 256, 0, stream>>>(x0, S4, x2, P, aW2, xeh);
    att_big_kernel<<<N_NODES / 8, 256, 0, stream>>>(xeh, ei0, ei1, aW2, ab2, y, YS);

    // final BN3 + fc
    prepF_kernel<<<1, 64, 0, stream>>>(YS, P, g3, be3, fW, fb);
    final_kernel<<<(50000 + 255) / 256, 256, 0, stream>>>((const float4*)y, P, (float2*)d_out);
}

// Round 11
// 325.272 us; speedup vs baseline: 1.9761x; 1.0716x over previous
//
#include <hip/hip_runtime.h>
#include <hip/hip_fp16.h>

#define N_NODES 100000
#define KN 32
#define EPS 1e-5f
#define NSLOT 128

// ---------------- workspace layout (float offsets) ----------------
#define OFF_X0   0          // [100000]   normalized scalar input
#define OFF_XEH  500000     // [100000*24 ushorts] packed fp16 xe2 rows: 18 xe, 2 pad, 3 q, pad
#define OFF_Z1Q  1800000    // [100000*8 ushorts = 1.6MB] layer1 records: x0,S0,S1,S2,q0,q1,q2,pad
#define OFF_S4   2500000    // [100000*4] layer0 per-head weighted sums (float4)
#define OFF_X2   2900000    // [100000*18] layer1 raw output (fp32)
#define OFF_Y    4700000    // [100000*18] layer2 raw output (fp32)
#define OFF_TX   6500000    // [16]   x sum/ss
#define OFF_SS   6500016    // [128*8]  S slotted stats
#define OFF_X2S  6501040    // [128*36] x2 slotted stats
#define OFF_YS   6505648    // [128*36] y slotted stats
#define OFF_P    6510256    // [1024] derived params
// P: 0 s0, 1 t0 | 2..4 A | 5..7 B | 8..10 C | 11 ew0, 12 ew1
//    16..87 M1(4x18), 88..105 c1 | 112..507 M2(22x18), 508..525 c2
//    528..545 wf, 546 cf | 548..559 PM1(4x3), 560..562 pc1

__device__ inline float2 h2f2(unsigned int w) {
    __half2 h = *reinterpret_cast<__half2*>(&w);
    return __half22float2(h);
}

// ---------------- stats of scalar input x (vectorized) ----------------
__global__ __launch_bounds__(256)
void statsx_kernel(const float4* __restrict__ x4, float* __restrict__ acc) {
    int i = blockIdx.x * 256 + threadIdx.x;
    float s = 0.f, ss = 0.f;
    if (i < 25000) {
        float4 v = x4[i];
        s = v.x + v.y + v.z + v.w;
        ss = v.x * v.x + v.y * v.y + v.z * v.z + v.w * v.w;
    }
#pragma unroll
    for (int off = 32; off > 0; off >>= 1) {
        s  += __shfl_xor(s,  off, 64);
        ss += __shfl_xor(ss, off, 64);
    }
    __shared__ float ls[4], lss[4];
    int wid = threadIdx.x >> 6;
    if ((threadIdx.x & 63) == 0) { ls[wid] = s; lss[wid] = ss; }
    __syncthreads();
    if (threadIdx.x == 0) {
        atomicAdd(&acc[0], ls[0] + ls[1] + ls[2] + ls[3]);
        atomicAdd(&acc[1], lss[0] + lss[1] + lss[2] + lss[3]);
    }
}

// ---------------- prep0: BN0 fold + layer0 score constants ----------------
__global__ void prep0_kernel(const float* __restrict__ T, float* __restrict__ P,
                             const float* g0, const float* be0,
                             const float* W0, const float* b0,
                             const float* aW0, const float* ab0) {
    if (threadIdx.x || blockIdx.x) return;
    float mu  = T[0] / (float)N_NODES;
    float var = T[1] / (float)N_NODES - mu * mu;
    float inv = rsqrtf(var + EPS);
    float s0 = inv * g0[0];
    P[0] = s0; P[1] = be0[0] - mu * s0;
    for (int h = 0; h < 3; ++h) {
        float A = 0.f, B = 0.f, Cc = 0.f;
        for (int f = 0; f < 6; ++f) {
            A  = fmaf(W0[h * 6 + f], aW0[f], A);
            B  = fmaf(W0[h * 6 + f], aW0[6 + f], B);
            Cc = fmaf(b0[h * 6 + f], aW0[f] + aW0[6 + f], Cc);
        }
        P[2 + h] = A; P[5 + h] = B; P[8 + h] = Cc + ab0[0];
    }
    P[11] = aW0[12]; P[12] = aW0[13];
}

// ---------------- x0 = BN0(x), vectorized ----------------
__global__ void x0_kernel(const float4* __restrict__ x4, const float* __restrict__ P,
                          float4* __restrict__ x0) {
    int i = blockIdx.x * blockDim.x + threadIdx.x;
    if (i < 25000) {
        float4 v = x4[i];
        float s = P[0], t = P[1];
        x0[i] = make_float4(fmaf(v.x, s, t), fmaf(v.y, s, t), fmaf(v.z, s, t), fmaf(v.w, s, t));
    }
}

// ---------------- layer0 attention + fused S stats ----------------
__global__ __launch_bounds__(256)
void att0_kernel(const float* __restrict__ x0,
                 const int* __restrict__ ei0, const int* __restrict__ ei1,
                 const float2* __restrict__ e2,
                 const float* __restrict__ P, float4* __restrict__ S4,
                 float* __restrict__ SS) {
    int hw = threadIdx.x >> 5;
    int node = blockIdx.x * 8 + hw;          // grid is exactly N/8 blocks
    int k = threadIdx.x & 31;
    int eidx = node * KN + k;
    int s = ei0[eidx], d = ei1[eidx];
    float xs = x0[s], xd = x0[d];
    float2 ef = e2[eidx];
    float eb = fmaf(ef.x, P[11], ef.y * P[12]);
    float sc0 = fmaf(xs, P[2], fmaf(xd, P[5], P[8]  + eb));
    float sc1 = fmaf(xs, P[3], fmaf(xd, P[6], P[9]  + eb));
    float sc2 = fmaf(xs, P[4], fmaf(xd, P[7], P[10] + eb));
    float m0 = sc0, m1 = sc1, m2 = sc2;
#pragma unroll
    for (int off = 16; off > 0; off >>= 1) {
        m0 = fmaxf(m0, __shfl_xor(m0, off, 32));
        m1 = fmaxf(m1, __shfl_xor(m1, off, 32));
        m2 = fmaxf(m2, __shfl_xor(m2, off, 32));
    }
    float w0 = __expf(sc0 - m0), w1 = __expf(sc1 - m1), w2 = __expf(sc2 - m2);
    float l0 = w0, l1 = w1, l2 = w2;
    float a0 = w0 * xs, a1 = w1 * xs, a2 = w2 * xs;
#pragma unroll
    for (int off = 16; off > 0; off >>= 1) {
        l0 += __shfl_xor(l0, off, 32); a0 += __shfl_xor(a0, off, 32);
        l1 += __shfl_xor(l1, off, 32); a1 += __shfl_xor(a1, off, 32);
        l2 += __shfl_xor(l2, off, 32); a2 += __shfl_xor(a2, off, 32);
    }
    __shared__ float sS[8][4];
    if (k == 0) {
        float v0 = a0 / l0, v1 = a1 / l1, v2 = a2 / l2;
        S4[node] = make_float4(v0, v1, v2, 0.f);
        sS[hw][0] = v0; sS[hw][1] = v1; sS[hw][2] = v2;
    }
    __syncthreads();
    if (threadIdx.x < 3) {
        float ps = 0.f, pss = 0.f;
#pragma unroll
        for (int h = 0; h < 8; ++h) { float v = sS[h][threadIdx.x]; ps += v; pss = fmaf(v, v, pss); }
        int slot = (blockIdx.x & (NSLOT - 1)) * 8;
        atomicAdd(&SS[slot + threadIdx.x], ps);
        atomicAdd(&SS[slot + 4 + threadIdx.x], pss);
    }
}

// ---------------- prep1: reduce S slots, fold BN1 into M1 (4x18)+c1, PM1/pc1 ----------------
__global__ void prep1_kernel(const float* __restrict__ SS, float* __restrict__ P,
                             const float* W0, const float* g1, const float* be1,
                             const float* W1, const float* b1,
                             const float* aW1, const float* ab1) {
    __shared__ float muS[3], varS[3], alpha[18], beta[18], sM1[4][18], sc1[18];
    int t = threadIdx.x;
    if (t < 3) {
        float s = 0.f, ss = 0.f;
#pragma unroll 8
        for (int i = 0; i < NSLOT; ++i) { s += SS[i * 8 + t]; ss += SS[i * 8 + 4 + t]; }
        float mu = s / (float)N_NODES;
        muS[t] = mu; varS[t] = ss / (float)N_NODES - mu * mu;
    }
    __syncthreads();
    if (t < 18) {
        int h = t / 6;
        float w = W0[t] / (float)KN;
        float inv1 = rsqrtf(varS[h] * w * w + EPS);
        float gg = inv1 * g1[t];
        alpha[t] = w * gg;
        beta[t]  = be1[t] - w * gg * muS[h];
    }
    __syncthreads();
    if (t < 18) {
        int j = t;
        float* M1 = P + 16; float* c1 = P + 88;
        float m0 = W1[j];
        sM1[0][j] = m0; M1[j] = m0;
        for (int h = 0; h < 3; ++h) {
            float acc = 0.f;
            for (int f = 0; f < 6; ++f) acc = fmaf(alpha[h * 6 + f], W1[(1 + h * 6 + f) * 18 + j], acc);
            sM1[1 + h][j] = acc; M1[(1 + h) * 18 + j] = acc;
        }
        float cc = b1[j];
        for (int c = 0; c < 18; ++c) cc = fmaf(beta[c], W1[(1 + c) * 18 + j], cc);
        sc1[j] = cc; c1[j] = cc;
    }
    __syncthreads();
    if (t < 12) {                       // PM1[c][h] = sum_f M1[c][h*6+f]*aW1[f]
        int c = t / 3, h = t - c * 3;
        float acc = 0.f;
        for (int f = 0; f < 6; ++f) acc = fmaf(sM1[c][h * 6 + f], aW1[f], acc);
        P[548 + c * 3 + h] = acc;
    } else if (t < 15) {                // pc1[h] = sum_f c1[h*6+f]*aW1[f] + ab1
        int h = t - 12;
        float acc = ab1[0];
        for (int f = 0; f < 6; ++f) acc = fmaf(sc1[h * 6 + f], aW1[f], acc);
        P[560 + h] = acc;
    }
}

// ---------------- zq1: per node, pack [x0,S0,S1,S2,q0,q1,q2,pad] fp16 (16B) ----------------
__global__ void zq1_kernel(const float* __restrict__ x0, const float4* __restrict__ S4,
                           const float* __restrict__ P, const float* __restrict__ aW1,
                           uint4* __restrict__ z1q1) {
    int n = blockIdx.x * blockDim.x + threadIdx.x;
    if (n >= N_NODES) return;
    float xv = x0[n];
    float4 S = S4[n];
    const float* M1 = P + 16; const float* c1 = P + 88;
    float row[18];
#pragma unroll
    for (int j = 0; j < 18; ++j) {
        float r = c1[j];
        r = fmaf(xv,  M1[j],      r);
        r = fmaf(S.x, M1[18 + j], r);
        r = fmaf(S.y, M1[36 + j], r);
        r = fmaf(S.z, M1[54 + j], r);
        row[j] = r;
    }
    float q0 = 0.f, q1 = 0.f, q2 = 0.f;
#pragma unroll
    for (int f = 0; f < 6; ++f) {
        float a = aW1[6 + f];
        q0 = fmaf(row[f], a, q0);
        q1 = fmaf(row[6 + f], a, q1);
        q2 = fmaf(row[12 + f], a, q2);
    }
    union { unsigned short u[8]; uint4 v; } pk;
    pk.u[0] = __half_as_ushort(__float2half(xv));
    pk.u[1] = __half_as_ushort(__float2half(S.x));
    pk.u[2] = __half_as_ushort(__float2half(S.y));
    pk.u[3] = __half_as_ushort(__float2half(S.z));
    pk.u[4] = __half_as_ushort(__float2half(q0));
    pk.u[5] = __half_as_ushort(__float2half(q1));
    pk.u[6] = __half_as_ushort(__float2half(q2));
    pk.u[7] = 0;
    z1q1[n] = pk.v;
}

// ---------------- layer1 attention on z-records: 2 gather requests/edge ----------------
__global__ __launch_bounds__(256)
void att_z1_kernel(const uint4* __restrict__ z1q1,
                   const int* __restrict__ ei0, const int* __restrict__ ei1,
                   const float* __restrict__ P,
                   float* __restrict__ out, float* __restrict__ slots) {
    int hw = threadIdx.x >> 5;
    int node = blockIdx.x * 8 + hw;          // grid exactly N/8
    int k = threadIdx.x & 31;
    int eidx = node * KN + k;
    int s = ei0[eidx], d = ei1[eidx];
    uint4 Rs = z1q1[s];
    uint4 Rd = z1q1[d];
    float2 z01 = h2f2(Rs.x), z23 = h2f2(Rs.y);
    float zc0 = z01.x, zc1 = z01.y, zc2 = z23.x, zc3 = z23.y;
    float2 q01 = h2f2(Rd.z), q23 = h2f2(Rd.w);
    const float* PM = P + 548;   // PM[c*3+h]
    const float* pc = P + 560;
    float sc0 = pc[0] + q01.x, sc1 = pc[1] + q01.y, sc2 = pc[2] + q23.x;
    sc0 = fmaf(zc0, PM[0], fmaf(zc1, PM[3], fmaf(zc2, PM[6], fmaf(zc3, PM[9],  sc0))));
    sc1 = fmaf(zc0, PM[1], fmaf(zc1, PM[4], fmaf(zc2, PM[7], fmaf(zc3, PM[10], sc1))));
    sc2 = fmaf(zc0, PM[2], fmaf(zc1, PM[5], fmaf(zc2, PM[8], fmaf(zc3, PM[11], sc2))));
    float m0 = sc0, m1 = sc1, m2 = sc2;
#pragma unroll
    for (int off = 16; off > 0; off >>= 1) {
        m0 = fmaxf(m0, __shfl_xor(m0, off, 32));
        m1 = fmaxf(m1, __shfl_xor(m1, off, 32));
        m2 = fmaxf(m2, __shfl_xor(m2, off, 32));
    }
    float w0 = __expf(sc0 - m0), w1 = __expf(sc1 - m1), w2 = __expf(sc2 - m2);
    float l0 = w0, l1 = w1, l2 = w2;
    float A[3][4];
#pragma unroll
    for (int c = 0; c < 4; ++c) {
        float z = (c == 0) ? zc0 : (c == 1) ? zc1 : (c == 2) ? zc2 : zc3;
        A[0][c] = w0 * z; A[1][c] = w1 * z; A[2][c] = w2 * z;
    }
#pragma unroll
    for (int off = 16; off > 0; off >>= 1) {
        l0 += __shfl_xor(l0, off, 32);
        l1 += __shfl_xor(l1, off, 32);
        l2 += __shfl_xor(l2, off, 32);
#pragma unroll
        for (int h = 0; h < 3; ++h)
#pragma unroll
            for (int c = 0; c < 4; ++c) A[h][c] += __shfl_xor(A[h][c], off, 32);
    }
    __shared__ float so[8][18];
    if (k < 18) {                         // parallel epilogue: lane t computes channel t
        int t = k;
        int h = t / 6;
        float lh = (h == 0) ? l0 : (h == 1) ? l1 : l2;
        float Ah0 = (h == 0) ? A[0][0] : (h == 1) ? A[1][0] : A[2][0];
        float Ah1 = (h == 0) ? A[0][1] : (h == 1) ? A[1][1] : A[2][1];
        float Ah2 = (h == 0) ? A[0][2] : (h == 1) ? A[1][2] : A[2][2];
        float Ah3 = (h == 0) ? A[0][3] : (h == 1) ? A[1][3] : A[2][3];
        const float* M1 = P + 16; const float* c1 = P + 88;
        float acc = Ah0 * M1[t] + Ah1 * M1[18 + t] + Ah2 * M1[36 + t] + Ah3 * M1[54 + t];
        float inv = 1.f / (lh * (float)KN);
        float x2v = fmaf(acc, inv, c1[t] * (1.f / (float)KN));
        out[(size_t)node * 18 + t] = x2v;
        so[hw][t] = x2v;
    }
    __syncthreads();
    if (threadIdx.x < 18) {
        int t = threadIdx.x;
        float ps = 0.f, pss = 0.f;
#pragma unroll
        for (int h = 0; h < 8; ++h) { float vv = so[h][t]; ps += vv; pss = fmaf(vv, vv, pss); }
        int slot = (blockIdx.x & (NSLOT - 1)) * 36;
        atomicAdd(&slots[slot + t], ps);
        atomicAdd(&slots[slot + 18 + t], pss);
    }
}

// ---------------- prep2: reduce slots, fold BN1+BN2 into M2 (22x18) + c2 ----------------
__global__ void prep2_kernel(const float* __restrict__ SS, const float* __restrict__ X2S,
                             float* __restrict__ P,
                             const float* W0, const float* g1, const float* be1,
                             const float* g2, const float* be2,
                             const float* W2, const float* b2) {
    __shared__ float muS[3], varS[3], alpha[18], beta[18], gam[18], del[18];
    int t = threadIdx.x;
    if (t < 3) {
        float s = 0.f, ss = 0.f;
#pragma unroll 8
        for (int i = 0; i < NSLOT; ++i) { s += SS[i * 8 + t]; ss += SS[i * 8 + 4 + t]; }
        float mu = s / (float)N_NODES;
        muS[t] = mu; varS[t] = ss / (float)N_NODES - mu * mu;
    }
    if (t < 18) {
        float s = 0.f, ss = 0.f;
#pragma unroll 8
        for (int i = 0; i < NSLOT; ++i) { s += X2S[i * 36 + t]; ss += X2S[i * 36 + 18 + t]; }
        float mu2 = s / (float)N_NODES;
        float var2 = ss / (float)N_NODES - mu2 * mu2;
        float g = rsqrtf(var2 + EPS) * g2[t];
        gam[t] = g; del[t] = be2[t] - mu2 * g;
    }
    __syncthreads();
    if (t < 18) {
        int h = t / 6;
        float w = W0[t] / (float)KN;
        float inv1 = rsqrtf(varS[h] * w * w + EPS);
        float gg = inv1 * g1[t];
        alpha[t] = w * gg;
        beta[t]  = be1[t] - w * gg * muS[h];
    }
    __syncthreads();
    if (t < 18) {
        int j = t;
        float* M2 = P + 112; float* c2 = P + 508;
        M2[j] = W2[j];
        for (int h = 0; h < 3; ++h) {
            float acc = 0.f;
            for (int f = 0; f < 6; ++f) acc = fmaf(alpha[h * 6 + f], W2[(1 + h * 6 + f) * 18 + j], acc);
            M2[(1 + h) * 18 + j] = acc;
        }
        for (int c = 0; c < 18; ++c) M2[(4 + c) * 18 + j] = gam[c] * W2[(19 + c) * 18 + j];
        float cc = b2[j];
        for (int c = 0; c < 18; ++c) cc = fmaf(beta[c], W2[(1 + c) * 18 + j], cc);
        for (int c = 0; c < 18; ++c) cc = fmaf(del[c],  W2[(19 + c) * 18 + j], cc);
        c2[j] = cc;
    }
}

// ---------------- pack row[18] + q[3] into 24 fp16 (48B) ----------------
__device__ inline void pack_row(unsigned short* __restrict__ xeh, int n,
                                const float* row, float q0, float q1, float q2) {
    union { unsigned short u[24]; uint4 v[3]; } pk;
#pragma unroll
    for (int j = 0; j < 18; ++j) pk.u[j] = __half_as_ushort(__float2half(row[j]));
    pk.u[18] = 0; pk.u[19] = 0;
    pk.u[20] = __half_as_ushort(__float2half(q0));
    pk.u[21] = __half_as_ushort(__float2half(q1));
    pk.u[22] = __half_as_ushort(__float2half(q2));
    pk.u[23] = 0;
    uint4* dst = (uint4*)(xeh + (size_t)n * 24);
    dst[0] = pk.v[0]; dst[1] = pk.v[1]; dst[2] = pk.v[2];
}

// ---------------- xe2 = [x0,S,x2raw] @ M2 + c2 ; pack fp16 row+q ----------------
__global__ void xe2_kernel(const float* __restrict__ x0, const float4* __restrict__ S4,
                           const float* __restrict__ x2, const float* __restrict__ P,
                           const float* __restrict__ aW2,
                           unsigned short* __restrict__ xeh) {
    int n = blockIdx.x * blockDim.x + threadIdx.x;
    if (n >= N_NODES) return;
    float xv = x0[n];
    float4 S = S4[n];
    float xr[18];
    const float2* x2p = (const float2*)(x2 + (size_t)n * 18);
#pragma unroll
    for (int q = 0; q < 9; ++q) { float2 v = x2p[q]; xr[2 * q] = v.x; xr[2 * q + 1] = v.y; }
    const float* M2 = P + 112; const float* c2 = P + 508;
    float row[18];
#pragma unroll
    for (int j = 0; j < 18; ++j) {
        float r = c2[j];
        r = fmaf(xv,  M2[j],      r);
        r = fmaf(S.x, M2[18 + j], r);
        r = fmaf(S.y, M2[36 + j], r);
        r = fmaf(S.z, M2[54 + j], r);
#pragma unroll
        for (int c = 0; c < 18; ++c) r = fmaf(xr[c], M2[(4 + c) * 18 + j], r);
        row[j] = r;
    }
    float q0 = 0.f, q1 = 0.f, q2 = 0.f;
#pragma unroll
    for (int f = 0; f < 6; ++f) {
        float a = aW2[6 + f];
        q0 = fmaf(row[f], a, q0);
        q1 = fmaf(row[6 + f], a, q1);
        q2 = fmaf(row[12 + f], a, q2);
    }
    pack_row(xeh, n, row, q0, q1, q2);
}

// ---------------- big attention (layer 2), fp16 gathers + fused channel stats ----------------
__global__ __launch_bounds__(256)
void att_big_kernel(const unsigned short* __restrict__ xeh,
                    const int* __restrict__ ei0, const int* __restrict__ ei1,
                    const float* __restrict__ aW, const float* __restrict__ abp,
                    float* __restrict__ out, float* __restrict__ slots) {
    int hw = threadIdx.x >> 5;
    int node = blockIdx.x * 8 + hw;          // grid exactly N/8
    int k = threadIdx.x & 31;
    int eidx = node * KN + k;
    int s = ei0[eidx], d = ei1[eidx];
    const unsigned short* rs = xeh + (size_t)s * 24;
    uint4 A = *(const uint4*)rs;                 // halves 0..7
    uint4 B = *(const uint4*)(rs + 8);           // halves 8..15
    unsigned int C = *(const unsigned int*)(rs + 16);  // halves 16,17
    uint2 Q = *(const uint2*)(xeh + (size_t)d * 24 + 20); // halves 20..23
    float2 p01 = h2f2(A.x), p23 = h2f2(A.y), p45 = h2f2(A.z), p67 = h2f2(A.w);
    float2 p89 = h2f2(B.x), pab = h2f2(B.y), pcd = h2f2(B.z), pef = h2f2(B.w);
    float2 pgh = h2f2(C);
    float2 q01 = h2f2(Q.x), q2_ = h2f2(Q.y);
    float r[18];
    r[0]=p01.x; r[1]=p01.y; r[2]=p23.x; r[3]=p23.y; r[4]=p45.x; r[5]=p45.y;
    r[6]=p67.x; r[7]=p67.y; r[8]=p89.x; r[9]=p89.y; r[10]=pab.x; r[11]=pab.y;
    r[12]=pcd.x; r[13]=pcd.y; r[14]=pef.x; r[15]=pef.y; r[16]=pgh.x; r[17]=pgh.y;
    float a0 = aW[0], a1 = aW[1], a2 = aW[2], a3 = aW[3], a4 = aW[4], a5 = aW[5];
    float ab = abp[0];
    float sc0 = fmaf(r[0],a0, fmaf(r[1],a1, fmaf(r[2],a2, fmaf(r[3],a3, fmaf(r[4],a4, r[5]*a5))))) + q01.x + ab;
    float sc1 = fmaf(r[6],a0, fmaf(r[7],a1, fmaf(r[8],a2, fmaf(r[9],a3, fmaf(r[10],a4, r[11]*a5))))) + q01.y + ab;
    float sc2 = fmaf(r[12],a0, fmaf(r[13],a1, fmaf(r[14],a2, fmaf(r[15],a3, fmaf(r[16],a4, r[17]*a5))))) + q2_.x + ab;
    float m0 = sc0, m1 = sc1, m2 = sc2;
#pragma unroll
    for (int off = 16; off > 0; off >>= 1) {
        m0 = fmaxf(m0, __shfl_xor(m0, off, 32));
        m1 = fmaxf(m1, __shfl_xor(m1, off, 32));
        m2 = fmaxf(m2, __shfl_xor(m2, off, 32));
    }
    float w0 = __expf(sc0 - m0), w1 = __expf(sc1 - m1), w2 = __expf(sc2 - m2);
    float l0 = w0, l1 = w1, l2 = w2;
    float v[18];
#pragma unroll
    for (int j = 0; j < 6; ++j) {
        v[j]      = w0 * r[j];
        v[6 + j]  = w1 * r[6 + j];
        v[12 + j] = w2 * r[12 + j];
    }
#pragma unroll
    for (int off = 16; off > 0; off >>= 1) {
        l0 += __shfl_xor(l0, off, 32);
        l1 += __shfl_xor(l1, off, 32);
        l2 += __shfl_xor(l2, off, 32);
#pragma unroll
        for (int j = 0; j < 18; ++j) v[j] += __shfl_xor(v[j], off, 32);
    }
    __shared__ float so[8][18];
    if (k == 0) {
        float i0 = 1.f / (l0 * (float)KN);
        float i1 = 1.f / (l1 * (float)KN);
        float i2 = 1.f / (l2 * (float)KN);
        size_t base = (size_t)node * 18;
#pragma unroll
        for (int j = 0; j < 6; ++j) {
            float o0 = v[j] * i0, o1 = v[6 + j] * i1, o2 = v[12 + j] * i2;
            out[base + j] = o0;      so[hw][j] = o0;
            out[base + 6 + j] = o1;  so[hw][6 + j] = o1;
            out[base + 12 + j] = o2; so[hw][12 + j] = o2;
        }
    }
    __syncthreads();
    if (threadIdx.x < 18) {
        int t = threadIdx.x;
        float ps = 0.f, pss = 0.f;
#pragma unroll
        for (int h = 0; h < 8; ++h) { float vv = so[h][t]; ps += vv; pss = fmaf(vv, vv, pss); }
        int slot = (blockIdx.x & (NSLOT - 1)) * 36;
        atomicAdd(&slots[slot + t], ps);
        atomicAdd(&slots[slot + 18 + t], pss);
    }
}

// ---------------- prepF: reduce Y slots, fold BN3 into final dot ----------------
__global__ void prepF_kernel(const float* __restrict__ YS, float* __restrict__ P,
                             const float* g3, const float* be3,
                             const float* fW, const float* fb) {
    __shared__ float part[18];
    int t = threadIdx.x;
    if (t < 18) {
        float s = 0.f, ss = 0.f;
#pragma unroll 8
        for (int i = 0; i < NSLOT; ++i) { s += YS[i * 36 + t]; ss += YS[i * 36 + 18 + t]; }
        float mu = s / (float)N_NODES;
        float var = ss / (float)N_NODES - mu * mu;
        float g = rsqrtf(var + EPS) * g3[t];
        P[528 + t] = g * fW[t];
        part[t] = (be3[t] - mu * g) * fW[t];
    }
    __syncthreads();
    if (t == 0) {
        float cf = fb[0];
        for (int j = 0; j < 18; ++j) cf += part[j];
        P[546] = cf;
    }
}

// ---------------- final: out = y @ wf + cf (2 nodes/thread, float4 loads) ----------------
__global__ __launch_bounds__(256)
void final_kernel(const float4* __restrict__ y4, const float* __restrict__ P,
                  float2* __restrict__ out2) {
    int i = blockIdx.x * blockDim.x + threadIdx.x;
    if (i >= 50000) return;
    const float4* yp = y4 + (size_t)i * 9;
    float a[36];
#pragma unroll
    for (int q = 0; q < 9; ++q) {
        float4 v = yp[q];
        a[4 * q] = v.x; a[4 * q + 1] = v.y; a[4 * q + 2] = v.z; a[4 * q + 3] = v.w;
    }
    float cf = P[546];
    float acc0 = cf, acc1 = cf;
#pragma unroll
    for (int j = 0; j < 18; ++j) {
        float w = P[528 + j];
        acc0 = fmaf(a[j], w, acc0);
        acc1 = fmaf(a[18 + j], w, acc1);
    }
    out2[i] = make_float2(acc0, acc1);
}

extern "C" void kernel_launch(void* const* d_in, const int* in_sizes, int n_in,
                              void* d_out, int out_size, void* d_ws, size_t ws_size,
                              hipStream_t stream) {
    const float* x   = (const float*)d_in[0];
    const int*   ei  = (const int*)d_in[1];
    const float* e   = (const float*)d_in[2];
    const float* W0  = (const float*)d_in[3];
    const float* b0  = (const float*)d_in[4];
    const float* aW0 = (const float*)d_in[5];
    const float* ab0 = (const float*)d_in[6];
    const float* W1  = (const float*)d_in[7];
    const float* b1  = (const float*)d_in[8];
    const float* aW1 = (const float*)d_in[9];
    const float* ab1 = (const float*)d_in[10];
    const float* W2  = (const float*)d_in[11];
    const float* b2  = (const float*)d_in[12];
    const float* aW2 = (const float*)d_in[13];
    const float* ab2 = (const float*)d_in[14];
    const float* g0  = (const float*)d_in[15];
    const float* be0 = (const float*)d_in[16];
    const float* g1  = (const float*)d_in[17];
    const float* be1 = (const float*)d_in[18];
    const float* g2  = (const float*)d_in[19];
    const float* be2 = (const float*)d_in[20];
    const float* g3  = (const float*)d_in[21];
    const float* be3 = (const float*)d_in[22];
    const float* fW  = (const float*)d_in[23];
    const float* fb  = (const float*)d_in[24];

    const int* ei0 = ei;
    const int* ei1 = ei + (size_t)N_NODES * KN;

    float*  ws  = (float*)d_ws;
    float*  x0  = ws + OFF_X0;
    unsigned short* xeh = (unsigned short*)(ws + OFF_XEH);
    uint4*  z1q1 = (uint4*)(ws + OFF_Z1Q);
    float4* S4  = (float4*)(ws + OFF_S4);
    float*  x2  = ws + OFF_X2;
    float*  y   = ws + OFF_Y;
    float*  TX  = ws + OFF_TX;
    float*  SS  = ws + OFF_SS;
    float*  X2S = ws + OFF_X2S;
    float*  YS  = ws + OFF_YS;
    float*  P   = ws + OFF_P;

    // zero all stats accumulators (TX..P region)
    hipMemsetAsync(TX, 0, (OFF_P - OFF_TX) * sizeof(float), stream);

    // stage 0: BN0
    statsx_kernel<<<98, 256, 0, stream>>>((const float4*)x, TX);
    prep0_kernel<<<1, 1, 0, stream>>>(TX, P, g0, be0, W0, b0, aW0, ab0);
    x0_kernel<<<98, 256, 0, stream>>>((const float4*)x, P, (float4*)x0);

    // layer 0 (rank-1): S per node, fused S stats
    att0_kernel<<<N_NODES / 8, 256, 0, stream>>>(x0, ei0, ei1, (const float2*)e, P, S4, SS);

    // layer 1 (z-record scheme: 2 gather requests/edge)
    prep1_kernel<<<1, 64, 0, stream>>>(SS, P, W0, g1, be1, W1, b1, aW1, ab1);
    zq1_kernel<<<(N_NODES + 255) / 256, 256, 0, stream>>>(x0, S4, P, aW1, z1q1);
    att_z1_kernel<<<N_NODES / 8, 256, 0, stream>>>(z1q1, ei0, ei1, P, x2, X2S);

    // layer 2 (unchanged control)
    prep2_kernel<<<1, 64, 0, stream>>>(SS, X2S, P, W0, g1, be1, g2, be2, W2, b2);
    xe2_kernel<<<(N_NODES + 255) / 256, 256, 0, stream>>>(x0, S4, x2, P, aW2, xeh);
    att_big_kernel<<<N_NODES / 8, 256, 0, stream>>>(xeh, ei0, ei1, aW2, ab2, y, YS);

    // final BN3 + fc
    prepF_kernel<<<1, 64, 0, stream>>>(YS, P, g3, be3, fW, fb);
    final_kernel<<<(50000 + 255) / 256, 256, 0, stream>>>((const float4*)y, P, (float2*)d_out);
}